// Round 18
// baseline (561.549 us; speedup 1.0000x reference)
//
#include <hip/hip_runtime.h>
#include <hip/hip_bf16.h>

// ---------- constants ----------
#define S_ 1024
#define H_ 2048
#define NH_ 16
#define KVH_ 4
#define HD_ 128
#define IM_ 1408
#define ISH_ 5632
#define E_ 8

typedef __bf16 bf16x8 __attribute__((ext_vector_type(8)));
typedef float f32x4 __attribute__((ext_vector_type(4)));

typedef unsigned int __attribute__((address_space(1))) as1_u32;
typedef unsigned int __attribute__((address_space(3))) as3_u32;

__device__ __forceinline__ void gload16(const void* g, void* l) {
  __builtin_amdgcn_global_load_lds((const as1_u32*)g, (as3_u32*)l, 16, 0, 0);
}

__device__ __forceinline__ short f2bf(float f) {
  unsigned u = __float_as_uint(f);
  u = u + 0x7FFFu + ((u >> 16) & 1u);   // RTNE
  return (short)(u >> 16);
}

__device__ __forceinline__ f32x4 mfma16(bf16x8 a, bf16x8 b, f32x4 c) {
  return __builtin_amdgcn_mfma_f32_16x16x32_bf16(a, b, c, 0, 0, 0);
}

template<bool MAXOP>
__device__ __forceinline__ float block_reduce(float v, float* sbuf) {
  #pragma unroll
  for (int o = 32; o >= 1; o >>= 1) {
    float t = __shfl_down(v, o);
    v = MAXOP ? fmaxf(v, t) : (v + t);
  }
  int lane = threadIdx.x & 63, w = threadIdx.x >> 6;
  if (lane == 0) sbuf[w] = v;
  __syncthreads();
  float r = sbuf[0];
  #pragma unroll
  for (int i = 1; i < 4; i++) r = MAXOP ? fmaxf(r, sbuf[i]) : (r + sbuf[i]);
  __syncthreads();
  return r;
}

// ---------- mega kernel: all weight transposes + prep + rmsnorm1 in ONE dispatch ----------
struct TransDesc {
  const float* src; short* dst;
  int R, C, tx, perz, base;
  long long srcZ, dstZ;
};
struct TransAll { TransDesc d[10]; };

#define TGRP 1096   // 16*68 + 8 pad dwords

__global__ __launch_bounds__(256) void mega_k(TransAll ta, int transBlocks,
                                              const int* pos_ids, float* ct, float* st,
                                              const float* qb, const float* kb, const float* vb,
                                              float* biasCat, int* counts,
                                              const float* hidden, const float* ln1_w,
                                              short* x1) {
  __shared__ float tile[4 * TGRP];
  __shared__ float sbuf[4];
  const int bid = blockIdx.x;
  const int t = threadIdx.x;
  if (bid < transBlocks) {
    int w = 0;
    #pragma unroll
    for (int i = 1; i < 10; i++) if (bid >= ta.d[i].base) w = i;
    const TransDesc& D = ta.d[w];
    int local = bid - D.base;
    int z = local / D.perz, rem = local - z * D.perz;
    int by = rem / D.tx, bx = rem - by * D.tx;
    const float* src = D.src + (long long)z * D.srcZ;
    short* dst = D.dst + (long long)z * D.dstZ;
    const int r0 = by * 64, c0 = bx * 64;
    const int C = D.C, R = D.R;
    #pragma unroll
    for (int i = 0; i < 4; i++) {
      int idx = t + i * 256;                 // 0..1023 float4s
      int row = idx >> 4, c4 = (idx & 15) * 4;
      f32x4 v = __builtin_nontemporal_load(
          (const f32x4*)&src[(size_t)(r0 + row) * C + c0 + c4]);
      *(f32x4*)&tile[(row >> 4) * TGRP + (row & 15) * 68 + c4] = v;
    }
    __syncthreads();
    const int col = t >> 2, seg = t & 3;
    const float* tp = &tile[seg * TGRP + col];
    short outv[16];
    #pragma unroll
    for (int j = 0; j < 16; j++)
      outv[j] = f2bf(tp[j * 68]);
    short* dp = &dst[(size_t)(c0 + col) * R + r0 + seg * 16];
    *(int4*)dp = *(const int4*)&outv[0];
    *(int4*)(dp + 8) = *(const int4*)&outv[8];
  } else if (bid < transBlocks + 256) {
    int pb = bid - transBlocks;
    if (pb == 0) {
      if (t < 16) counts[t] = 0;             // counts[8] + pos[8]
      for (int j = t; j < 3072; j += 256)
        biasCat[j] = (j < 2048) ? qb[j] : ((j < 2560) ? kb[j - 2048] : vb[j - 2560]);
    }
    int i = pb * 256 + t;                    // rope tables [0, 65536)
    int p = i >> 6, f = i & 63;
    float pos = (float)pos_ids[p];
    float inv = powf(1.0e6f, -(float)f * (1.f / 64.f));
    float a = pos * inv;
    ct[i] = cosf(a); st[i] = sinf(a);
  } else {
    // rmsnorm1 for token row tr (x1 bf16 only)
    int tr = bid - transBlocks - 256;        // [0, 1024)
    const float* xr = hidden + (long long)tr * H_;
    float ss = 0.f;
    for (int i = t; i < H_ / 4; i += 256) {
      float4 v = ((const float4*)xr)[i];
      ss += v.x * v.x + v.y * v.y + v.z * v.z + v.w * v.w;
    }
    ss = block_reduce<false>(ss, sbuf);
    float rs = rsqrtf(ss * (1.f / (float)H_) + 1e-6f);
    for (int i = t; i < H_; i += 256) {
      float xv = xr[i];
      x1[(long long)tr * H_ + i] = f2bf(xv * rs * ln1_w[i]);
    }
  }
}

// ---------- GEMM: A bf16 [M,K], B bf16 [N,K] (K-contig), BK=64, 2-phase dbuf ----------
// BK=64: 32 MFMA + 16 ds_read_b128 per barrier (2x the old BK=32) -> the
// per-step load latency is amortized over ~600cy of compute. LDS 64KB/block
// (2 blocks/CU -- regs already capped us there, so no occupancy loss).
// Both-sides swizzle in the 8-slot space: source col (t&7)^((t>>3)&7),
// read slot (kk*4+kg)^(li&7). Read undoes write -> correct k per fragment;
// bank usage = structural 2-way minimum.
// DETERMINISM: h2 chain (QKV, scores, PV, O-proj) has NO atomics - split-K
// writes per-chunk partials (EPI 0 + kc*strideC) reduced in fixed order by
// consumers. Only MoE scatter-adds (EPI 4/5, continuous path) use atomicAdd.
// EPI 0: C fp32 = alpha*acc, plain store at C + zc + kc*strideC (partials)
// EPI 2: C bf16 = acc (in-register full-K accumulation)
// EPI 4: expert: A row = off+m, atomicAdd(C[list[off+m]*ldc+n], scale[off+m]*acc)
// EPI 5: atomicAdd(C[m*ldc+n], scale[m]*acc)
// EPI 6: FUSED gate+up+silu, dense: B-tile = 64 gate rows + 64 up rows; C bf16.
// EPI 7: FUSED, expert-gathered: A row = list[off+m], C row = off+m.
struct GemmP {
  const short* A; long long strideA; int adiv; int lda;
  const short* B; long long strideB; int bdiv; int ldb;
  void* C; long long strideC; int cdiv; int ldc;
  const int* e_off; const int* e_cnt;
  const int* list; const float* scale;
  float alpha;
  int M, N, K;
  int cskip, ckb;
  int ksplit, kchunk;
  int upoff;
};

template<int EPI>
__device__ __forceinline__ void gemm_body(const GemmP& p, int bx, int by, int bz,
                                          short* As, short* Bs) {
  constexpr bool FUSED = (EPI == 6 || EPI == 7);
  constexpr bool GATH  = (EPI == 7);
  constexpr int BM = 128, BK = 64;
  const int zo = bz / p.ksplit;
  const int kc = bz - zo * p.ksplit;
  const int m0 = by * BM;
  const int n0 = bx * (FUSED ? 64 : 128);
  if (FUSED && n0 >= p.N) return;

  int off = 0, cnt = p.M;
  if constexpr (EPI == 4 || GATH) {
    off = p.e_off[zo]; cnt = p.e_cnt[zo];
    if (m0 >= cnt) return;
  }
  if (p.cskip && n0 >= m0 + BM) return;
  int kend = p.ckb ? min(m0 + BM, p.K) : p.K;
  const int kbeg = kc * p.kchunk;
  kend = min(kend, kbeg + p.kchunk);
  if (kbeg >= kend) return;

  const short* Ab = p.A + (long long)(zo / p.adiv) * p.strideA;
  const short* Bb = p.B + (long long)(zo / p.bdiv) * p.strideB;

  const int tid = threadIdx.x;
  const int lane = tid & 63, wid = tid >> 6;
  const int wr = wid >> 1, wc = wid & 1;
  const int kg = lane >> 4, li = lane & 15;

  // staging: per pass c in 0..3, thread t fills row (t>>3)+c*32, 16B slot (t&7);
  // source k-slot pre-swizzled by row&7 = (t>>3)&7 (pass-invariant).
  const int srow = tid >> 3;                 // [0,32)
  const int scol = (((tid & 7) ^ ((tid >> 3) & 7))) * 8;
  const short* aSrc[4];
  const short* bSrc[4];
  #pragma unroll
  for (int c = 0; c < 4; c++) {
    int ra = srow + c * 32;                  // [0,128)
    int gr;
    if constexpr (GATH)          { int rr = m0 + ra; if (rr >= cnt) rr = cnt - 1; gr = p.list[off + rr]; }
    else if constexpr (EPI == 4) { int rr = m0 + ra; if (rr >= cnt) rr = cnt - 1; gr = off + rr; }
    else                         gr = m0 + ra;
    aSrc[c] = Ab + (long long)gr * p.lda + scol;
    int br = FUSED ? ((ra < 64) ? (n0 + ra) : (p.upoff + n0 + ra - 64)) : (n0 + ra);
    bSrc[c] = Bb + (long long)br * p.ldb + scol;
  }

  f32x4 acc[4][4];
  #pragma unroll
  for (int i = 0; i < 4; i++)
    #pragma unroll
    for (int j = 0; j < 4; j++) acc[i][j] = (f32x4){0.f, 0.f, 0.f, 0.f};

  // stage first tile into buf 0 (8 gload16/thread per tile)
  #pragma unroll
  for (int c = 0; c < 4; c++) {
    gload16(aSrc[c] + kbeg, &As[tid * 8 + c * 2048]);
    gload16(bSrc[c] + kbeg, &Bs[tid * 8 + c * 2048]);
  }
  __syncthreads();

  const int r7 = li & 7;
  int brow[4];
  #pragma unroll
  for (int nj = 0; nj < 4; nj++)
    brow[nj] = FUSED ? (((nj & 2) ? 64 : 0) + wc * 32 + (nj & 1) * 16 + li)
                     : (wc * 64 + nj * 16 + li);

  int cur = 0;
  for (int k0 = kbeg; k0 < kend; k0 += BK) {
    const int nk = k0 + BK;
    if (nk < kend) {
      #pragma unroll
      for (int c = 0; c < 4; c++) {
        gload16(aSrc[c] + nk, &As[(cur ^ 1) * 8192 + tid * 8 + c * 2048]);
        gload16(bSrc[c] + nk, &Bs[(cur ^ 1) * 8192 + tid * 8 + c * 2048]);
      }
    }
    #pragma unroll
    for (int kk = 0; kk < 2; kk++) {
      const int sl = ((kk * 4 + kg) ^ r7) * 8;
      bf16x8 av[4], bv[4];
      #pragma unroll
      for (int mi = 0; mi < 4; mi++)
        av[mi] = *(const bf16x8*)&As[cur * 8192 + (wr * 64 + mi * 16 + li) * BK + sl];
      #pragma unroll
      for (int nj = 0; nj < 4; nj++)
        bv[nj] = *(const bf16x8*)&Bs[cur * 8192 + brow[nj] * BK + sl];
      #pragma unroll
      for (int mi = 0; mi < 4; mi++)
        #pragma unroll
        for (int nj = 0; nj < 4; nj++)
          acc[mi][nj] = mfma16(av[mi], bv[nj], acc[mi][nj]);
    }
    __syncthreads();
    cur ^= 1;
  }

  const long long zc = (long long)(zo / p.cdiv) * p.strideC;
  if constexpr (FUSED) {
    short* C = (short*)p.C;
    #pragma unroll
    for (int mi = 0; mi < 4; mi++) {
      #pragma unroll
      for (int nj = 0; nj < 2; nj++) {
        #pragma unroll
        for (int r = 0; r < 4; r++) {
          int ml = wr * 64 + mi * 16 + kg * 4 + r;
          int mg = m0 + ml;
          int ng = n0 + wc * 32 + nj * 16 + li;
          float g = acc[mi][nj][r], u = acc[mi][nj + 2][r];
          float gu = g * (1.f / (1.f + __expf(-g))) * u;
          if constexpr (GATH) {
            if (mg < cnt) C[(long long)(off + mg) * p.ldc + ng] = f2bf(gu);
          } else {
            C[(long long)mg * p.ldc + ng] = f2bf(gu);
          }
        }
      }
    }
  } else {
    #pragma unroll
    for (int mi = 0; mi < 4; mi++) {
      #pragma unroll
      for (int nj = 0; nj < 4; nj++) {
        #pragma unroll
        for (int r = 0; r < 4; r++) {
          int ml = wr * 64 + mi * 16 + kg * 4 + r;
          int nl2 = wc * 64 + nj * 16 + li;
          int mg = m0 + ml, ng = n0 + nl2;
          float v = acc[mi][nj][r] * p.alpha;
          if constexpr (EPI == 0) {
            float* C = (float*)p.C + zc + (long long)kc * p.strideC;
            C[(long long)mg * p.ldc + ng] = v;
          } else if constexpr (EPI == 2) {
            short* C = (short*)p.C + zc;
            C[(long long)mg * p.ldc + ng] = f2bf(v);
          } else if constexpr (EPI == 4) {
            if (mg < cnt) {
              float* C = (float*)p.C;
              int tok = p.list[off + mg];
              atomicAdd(&C[(long long)tok * p.ldc + ng], p.scale[off + mg] * v);
            }
          } else if constexpr (EPI == 5) {
            float* C = (float*)p.C;
            atomicAdd(&C[(long long)mg * p.ldc + ng], p.scale[mg] * v);
          }
        }
      }
    }
  }
}

template<int EPI>
__global__ __launch_bounds__(256) void gemm_bt(GemmP p) {
  __shared__ __align__(16) short As[2 * 128 * 64];
  __shared__ __align__(16) short Bs[2 * 128 * 64];
  gemm_body<EPI>(p, blockIdx.x, blockIdx.y, blockIdx.z, As, Bs);
}

// gu-dual: grid (22, 8, 12). z<8: expert e=z (EPI7, 22 n-tiles of 64).
// z in [8,12): shared (EPI6), n-tile = (z-8)*22 + x in [0,88). Zero dead blocks.
__global__ __launch_bounds__(256) void gemm_gu_dual(GemmP pe, GemmP ps) {
  __shared__ __align__(16) short As[2 * 128 * 64];
  __shared__ __align__(16) short Bs[2 * 128 * 64];
  int z = blockIdx.z;
  if (z < E_) gemm_body<7>(pe, blockIdx.x, blockIdx.y, z, As, Bs);
  else        gemm_body<6>(ps, (z - E_) * 22 + blockIdx.x, blockIdx.y, 0, As, Bs);
}

// generic dual (down-projections): z < z1 -> p1 (EPI1), else p2 (EPI2).
template<int EPI1, int EPI2>
__global__ __launch_bounds__(256) void gemm_dual(GemmP p1, GemmP p2, int z1) {
  __shared__ __align__(16) short As[2 * 128 * 64];
  __shared__ __align__(16) short Bs[2 * 128 * 64];
  int z = blockIdx.z;
  if (z < z1) gemm_body<EPI1>(p1, blockIdx.x, blockIdx.y, z, As, Bs);
  else        gemm_body<EPI2>(p2, blockIdx.x, blockIdx.y, z - z1, As, Bs);
}

// ---------- aux kernels ----------
// fused RoPE(q,k) + V-transpose reading QKV split-K partials (p0+p1+bias, fixed order)
__global__ __launch_bounds__(256) void rope_fused_k(const float* p0, const float* p1,
                                                    const float* bias, short* qr, short* kr,
                                                    short* vt, const float* ct, const float* st) {
  int i = blockIdx.x * 256 + threadIdx.x;          // [0, 3145728)
  if (i < 2097152) {                               // Q rope
    int t = i >> 11, j = i & 2047;
    int d = j & 127, f = d & 63;
    float c = ct[t * 64 + f], s = st[t * 64 + f];
    long long base = (long long)t * 3072;
    float xv = p0[base + j] + p1[base + j] + bias[j];
    int jo = (d < 64) ? j + 64 : j - 64;
    float ov = p0[base + jo] + p1[base + jo] + bias[jo];
    if (d < 64) ov = -ov;
    qr[i] = f2bf(xv * c + ov * s);
  } else if (i < 2621440) {                        // K rope
    int j = i - 2097152;
    int t = j >> 9, jj = j & 511;
    int d = jj & 127, f = d & 63;
    float c = ct[t * 64 + f], s = st[t * 64 + f];
    long long base = (long long)t * 3072 + 2048;
    float xv = p0[base + jj] + p1[base + jj] + bias[2048 + jj];
    int jo = (d < 64) ? jj + 64 : jj - 64;
    float ov = p0[base + jo] + p1[base + jo] + bias[2048 + jo];
    if (d < 64) ov = -ov;
    kr[j] = f2bf(xv * c + ov * s);
  } else {                                         // V transpose
    int j = i - 2621440;                           // kvh*131072 + d*1024 + s
    int kvh = j >> 17, rem = j & 131071;
    int d = rem >> 10, s_ = rem & 1023;
    long long idx = (long long)s_ * 3072 + 2560 + kvh * 128 + d;
    vt[j] = f2bf(p0[idx] + p1[idx] + bias[2560 + kvh * 128 + d]);
  }
}

// rmsnorm2 fused with O-proj partial reduction: h2 = p0+p1+hidden (fixed order),
// writes out=h2, x2=bf16(h2*rs*w), rs2.
__global__ __launch_bounds__(256) void rmsnorm2f_k(const float* p0, const float* p1,
                                                   const float* hid, const float* w,
                                                   short* x2, float* outp, float* rs_out) {
  __shared__ float rowbuf[H_];
  __shared__ float sbuf[4];
  int tr = blockIdx.x;
  long long base = (long long)tr * H_;
  float ss = 0.f;
  for (int i = threadIdx.x; i < H_; i += 256) {
    float hv = p0[base + i] + p1[base + i] + hid[base + i];
    rowbuf[i] = hv;
    ss += hv * hv;
  }
  ss = block_reduce<false>(ss, sbuf);
  float rs = rsqrtf(ss * (1.f / (float)H_) + 1e-6f);
  for (int i = threadIdx.x; i < H_; i += 256) {
    float hv = rowbuf[i];
    outp[base + i] = hv;
    x2[base + i] = f2bf(hv * rs * w[i]);
  }
  if (threadIdx.x == 0) rs_out[tr] = rs;
}

__global__ __launch_bounds__(256) void softmax_k(const float* sc, short* P) {
  __shared__ float sbuf[4];
  long long row = blockIdx.x;                      // h*1024+q
  int q = (int)(row & (S_ - 1));
  const float* sr = sc + row * S_;
  short* pr = P + row * S_;
  int L = q + 1;
  int Lcap = (q & ~127) + 128;                     // PV never reads beyond this
  float mx = -3.4e38f;
  for (int i = threadIdx.x; i < L; i += 256) mx = fmaxf(mx, sr[i]);
  mx = block_reduce<true>(mx, sbuf);
  float s = 0.f;
  for (int i = threadIdx.x; i < L; i += 256) s += __expf(sr[i] - mx);
  s = block_reduce<false>(s, sbuf);
  float inv = 1.f / s;
  for (int i = threadIdx.x; i < Lcap; i += 256) {
    float pv = (i < L) ? __expf(sr[i] - mx) * inv : 0.f;
    pr[i] = f2bf(pv);
  }
}

__global__ void router_k(const float* h2, const float* rs, const float* w2,
                         const float* rw, const float* sgw,
                         int* top_i, float* top_w, float* sg_sig, int* counts) {
  int t = blockIdx.x;
  int l = threadIdx.x;   // 64 threads
  float le[8] = {0, 0, 0, 0, 0, 0, 0, 0};
  float ls = 0.f;
  float r = rs[t];
  for (int k = l; k < H_; k += 64) {
    float xv = h2[(long long)t * H_ + k] * r * w2[k];
    ls += xv * sgw[k];
    const float* rk = rw + k * E_;
    #pragma unroll
    for (int e = 0; e < E_; e++) le[e] += xv * rk[e];
  }
  #pragma unroll
  for (int o = 32; o >= 1; o >>= 1) {
    ls += __shfl_down(ls, o);
    #pragma unroll
    for (int e = 0; e < E_; e++) le[e] += __shfl_down(le[e], o);
  }
  if (l == 0) {
    float m = le[0];
    for (int e = 1; e < E_; e++) m = fmaxf(m, le[e]);
    float pe[8], s = 0.f;
    for (int e = 0; e < E_; e++) { pe[e] = __expf(le[e] - m); s += pe[e]; }
    float inv = 1.f / s;
    for (int e = 0; e < E_; e++) pe[e] *= inv;
    int i1 = 0;
    for (int e = 1; e < E_; e++) if (pe[e] > pe[i1]) i1 = e;
    int i2 = -1;
    for (int e = 0; e < E_; e++) if (e != i1 && (i2 < 0 || pe[e] > pe[i2])) i2 = e;
    top_i[2 * t] = i1; top_i[2 * t + 1] = i2;
    top_w[2 * t] = pe[i1]; top_w[2 * t + 1] = pe[i2];
    sg_sig[t] = 1.f / (1.f + __expf(-ls));
    atomicAdd(&counts[i1], 1); atomicAdd(&counts[i2], 1);
  }
}

__global__ void scan_k(const int* counts, int* offs) {
  if (threadIdx.x == 0 && blockIdx.x == 0) {
    int s = 0;
    for (int e = 0; e < E_; e++) { offs[e] = s; s += counts[e]; }
  }
}

__global__ __launch_bounds__(256) void fill_k(const int* top_i, const float* top_w, const int* offs,
                                              int* pos, int* list, float* pw) {
  int t = blockIdx.x * 256 + threadIdx.x;
  if (t >= S_) return;
  for (int j = 0; j < 2; j++) {
    int e = top_i[2 * t + j];
    int p_ = atomicAdd(&pos[e], 1);
    int slot = offs[e] + p_;
    list[slot] = t; pw[slot] = top_w[2 * t + j];
  }
}

// ---------- host ----------
static GemmP mkp() {
  GemmP p{};
  p.adiv = 1; p.bdiv = 1; p.cdiv = 1; p.alpha = 1.f;
  p.ksplit = 1; p.kchunk = 1 << 30;
  p.upoff = 0;
  return p;
}

extern "C" void kernel_launch(void* const* d_in, const int* in_sizes, int n_in,
                              void* d_out, int out_size, void* d_ws, size_t ws_size,
                              hipStream_t stream) {
  const float* hidden   = (const float*)d_in[0];
  const int*   pos_ids  = (const int*)d_in[1];
  const float* ln1_w    = (const float*)d_in[2];
  const float* ln2_w    = (const float*)d_in[3];
  const float* q_w      = (const float*)d_in[4];
  const float* q_b      = (const float*)d_in[5];
  const float* k_w      = (const float*)d_in[6];
  const float* k_b      = (const float*)d_in[7];
  const float* v_w      = (const float*)d_in[8];
  const float* v_b      = (const float*)d_in[9];
  const float* o_w      = (const float*)d_in[10];
  const float* router_w = (const float*)d_in[11];
  const float* e_gate   = (const float*)d_in[12];
  const float* e_up     = (const float*)d_in[13];
  const float* e_down   = (const float*)d_in[14];
  const float* s_gate   = (const float*)d_in[15];
  const float* s_up     = (const float*)d_in[16];
  const float* s_down   = (const float*)d_in[17];
  const float* sg_w     = (const float*)d_in[18];
  float* out = (float*)d_out;

  char* base = (char*)d_ws;
  size_t off_ = 0;
  auto alc = [&](size_t nbytes) -> char* {
    off_ = (off_ + 255) & ~(size_t)255;
    char* p = base + off_;
    off_ += nbytes;
    return p;
  };
  short* qkvT = (short*)alc((size_t)3072 * H_ * 2);
  short* oT   = (short*)alc((size_t)H_ * H_ * 2);
  short* eguT = (short*)alc((size_t)E_ * 2816 * H_ * 2);
  short* edT  = (short*)alc((size_t)E_ * H_ * IM_ * 2);
  short* sguT = (short*)alc((size_t)11264 * H_ * 2);
  short* sdT  = (short*)alc((size_t)H_ * ISH_ * 2);
  short* x1      = (short*)alc((size_t)S_ * H_ * 2);
  float* qkv_p   = (float*)alc((size_t)2 * S_ * 3072 * 4);   // QKV split-K partials
  float* o_part  = (float*)alc((size_t)2 * S_ * H_ * 4);     // O-proj split-K partials
  float* biasCat = (float*)alc(3072 * 4);
  float* ct      = (float*)alc((size_t)S_ * 64 * 4);
  float* st      = (float*)alc((size_t)S_ * 64 * 4);
  short* qr      = (short*)alc((size_t)S_ * H_ * 2);
  short* kr      = (short*)alc((size_t)S_ * 512 * 2);
  short* vt      = (short*)alc((size_t)S_ * 512 * 2);
  short* attn    = (short*)alc((size_t)S_ * H_ * 2);
  short* x2      = (short*)alc((size_t)S_ * H_ * 2);
  float* rs2     = (float*)alc(S_ * 4);
  int*   top_i   = (int*)alc(2 * S_ * 4);
  float* top_w   = (float*)alc(2 * S_ * 4);
  float* sg_sig  = (float*)alc(S_ * 4);
  int*   counts  = (int*)alc(64);
  int*   pos     = counts + 8;
  int*   offs    = (int*)alc(32);
  int*   list    = (int*)alc(2 * S_ * 4);
  float* pw      = (float*)alc(2 * S_ * 4);
  char*  region  = alc(100663296);   // 96 MiB overlay
  float* scores  = (float*)region;                            // 64 MiB
  short* P       = (short*)(region + 67108864);               // 32 MiB
  short* gu_moeB = (short*)region;                            // reuse after attn
  short* gushB   = (short*)(region + 16777216);

  // 0) mega dispatch: all weight transposes + prep + rmsnorm1
  {
    TransAll ta{};
    int b = 0;
    auto add = [&](int i, const float* s, short* d, int R, int C, int tz,
                   long long sZ, long long dZ) {
      int tx = C / 64, ty = R / 64;
      ta.d[i] = TransDesc{s, d, R, C, tx, tx * ty, b, sZ, dZ};
      b += tx * ty * tz;
    };
    add(0, q_w, qkvT, H_, H_, 1, 0, 0);
    add(1, k_w, qkvT + (size_t)2048 * H_, H_, 512, 1, 0, 0);
    add(2, v_w, qkvT + (size_t)2560 * H_, H_, 512, 1, 0, 0);
    add(3, o_w, oT, H_, H_, 1, 0, 0);
    add(4, e_gate, eguT, H_, IM_, E_, (long long)H_ * IM_, (long long)2816 * H_);
    add(5, e_up, eguT + (size_t)1408 * H_, H_, IM_, E_, (long long)H_ * IM_, (long long)2816 * H_);
    add(6, e_down, edT, IM_, H_, E_, (long long)IM_ * H_, (long long)IM_ * H_);
    add(7, s_gate, sguT, H_, ISH_, 1, 0, 0);
    add(8, s_up, sguT + (size_t)5632 * H_, H_, ISH_, 1, 0, 0);
    add(9, s_down, sdT, ISH_, H_, 1, 0, 0);
    mega_k<<<b + 256 + 1024, 256, 0, stream>>>(ta, b, pos_ids, ct, st, q_b, k_b, v_b,
                                               biasCat, counts, hidden, ln1_w, x1);
  }

  // 2) fused QKV projection: split-K=2 -> partial buffers (no atomics)
  {
    GemmP p = mkp();
    p.A = x1; p.lda = H_;
    p.B = qkvT; p.ldb = H_;
    p.C = qkv_p; p.strideC = (long long)S_ * 3072; p.ldc = 3072;
    p.M = S_; p.N = 3072; p.K = H_;
    p.ksplit = 2; p.kchunk = 1024;
    gemm_bt<0><<<dim3(24, 8, 2), 256, 0, stream>>>(p);
  }

  // 3) fused RoPE(q,k) + V transpose, reducing the partials (p0+p1+bias)
  rope_fused_k<<<12288, 256, 0, stream>>>(qkv_p, qkv_p + (size_t)S_ * 3072, biasCat,
                                          qr, kr, vt, ct, st);

  // 4) scores = scale * Q K^T (causal tiles only)
  {
    GemmP p = mkp();
    p.A = qr; p.strideA = HD_; p.lda = H_;
    p.B = kr; p.strideB = HD_; p.bdiv = 4; p.ldb = 512;
    p.C = scores; p.strideC = (long long)S_ * S_; p.ldc = S_;
    p.alpha = 0.08838834764831845f;
    p.M = S_; p.N = S_; p.K = HD_; p.cskip = 1;
    gemm_bt<0><<<dim3(8, 8, NH_), 256, 0, stream>>>(p);
  }
  softmax_k<<<NH_ * S_, 256, 0, stream>>>(scores, P);
  // 5) attn = P @ V  (no split-K: in-register causal-K accumulation, bf16 store)
  {
    GemmP p = mkp();
    p.A = P; p.strideA = (long long)S_ * S_; p.lda = S_;
    p.B = vt; p.strideB = (long long)HD_ * S_; p.bdiv = 4; p.ldb = S_;
    p.C = attn; p.strideC = HD_; p.ldc = H_;
    p.M = S_; p.N = HD_; p.K = S_; p.ckb = 1;
    gemm_bt<2><<<dim3(1, 8, NH_), 256, 0, stream>>>(p);
  }
  // 6) O-proj: split-K=2 -> partial buffers (no atomics)
  {
    GemmP p = mkp();
    p.A = attn; p.lda = H_;
    p.B = oT; p.ldb = H_;
    p.C = o_part; p.strideC = (long long)S_ * H_; p.ldc = H_;
    p.M = S_; p.N = H_; p.K = H_;
    p.ksplit = 2; p.kchunk = 1024;
    gemm_bt<0><<<dim3(16, 8, 2), 256, 0, stream>>>(p);
  }

  // 7) rmsnorm2 fused with O-partial reduction: out = h2 = p0+p1+hidden;
  //    x2 = bf16(h2*rs*ln2_w); rs2. Deterministic -> stable router top-2.
  rmsnorm2f_k<<<S_, 256, 0, stream>>>(o_part, o_part + (size_t)S_ * H_, hidden,
                                      ln2_w, x2, out, rs2);

  // 8) router / top-2 / gather lists (reads out == h2; counts pre-zeroed in mega_k)
  router_k<<<S_, 64, 0, stream>>>(out, rs2, ln2_w, router_w, sg_w, top_i, top_w, sg_sig, counts);
  scan_k<<<1, 1, 0, stream>>>(counts, offs);
  fill_k<<<4, 256, 0, stream>>>(top_i, top_w, offs, pos, list, pw);

  // 9) MERGED gate+up+silu: expert (z<8, 22 n-tiles) + shared (z 8..11, n-tile
  //    = (z-8)*22+x) -> 2112 blocks, zero dead blocks.
  {
    GemmP pe = mkp();
    pe.A = x2; pe.lda = H_;
    pe.B = eguT; pe.strideB = (long long)2816 * H_; pe.ldb = H_;
    pe.C = gu_moeB; pe.ldc = IM_;
    pe.e_off = offs; pe.e_cnt = counts; pe.list = list;
    pe.M = S_; pe.N = IM_; pe.K = H_;
    pe.upoff = IM_;
    GemmP ps = mkp();
    ps.A = x2; ps.lda = H_;
    ps.B = sguT; ps.ldb = H_;
    ps.C = gushB; ps.ldc = ISH_;
    ps.M = S_; ps.N = ISH_; ps.K = H_;
    ps.upoff = ISH_;
    gemm_gu_dual<<<dim3(22, 8, 12), 256, 0, stream>>>(pe, ps);
  }

  // 10) MERGED down-projections: expert scatter-add (z<16) + shared (z 16..19).
  //     atomicAdd here is rounding-level nondeterminism only (continuous path).
  {
    GemmP pe = mkp();
    pe.A = gu_moeB; pe.lda = IM_;
    pe.B = edT; pe.strideB = (long long)H_ * IM_; pe.ldb = IM_;
    pe.C = out; pe.ldc = H_;
    pe.e_off = offs; pe.e_cnt = counts; pe.list = list; pe.scale = pw;
    pe.M = S_; pe.N = H_; pe.K = IM_;
    pe.ksplit = 2; pe.kchunk = 704;
    GemmP ps = mkp();
    ps.A = gushB; ps.lda = ISH_;
    ps.B = sdT; ps.ldb = ISH_;
    ps.C = out; ps.ldc = H_; ps.scale = sg_sig;
    ps.M = S_; ps.N = H_; ps.K = ISH_;
    ps.ksplit = 4; ps.kchunk = 1408;
    gemm_dual<4, 5><<<dim3(16, 8, E_ * 2 + 4), 256, 0, stream>>>(pe, ps, E_ * 2);
  }
}

// Round 19
// 555.859 us; speedup vs baseline: 1.0102x; 1.0102x over previous
//
#include <hip/hip_runtime.h>
#include <hip/hip_bf16.h>

// ---------- constants ----------
#define S_ 1024
#define H_ 2048
#define NH_ 16
#define KVH_ 4
#define HD_ 128
#define IM_ 1408
#define ISH_ 5632
#define E_ 8

typedef __bf16 bf16x8 __attribute__((ext_vector_type(8)));
typedef float f32x4 __attribute__((ext_vector_type(4)));

typedef unsigned int __attribute__((address_space(1))) as1_u32;
typedef unsigned int __attribute__((address_space(3))) as3_u32;

__device__ __forceinline__ void gload16(const void* g, void* l) {
  __builtin_amdgcn_global_load_lds((const as1_u32*)g, (as3_u32*)l, 16, 0, 0);
}

__device__ __forceinline__ short f2bf(float f) {
  unsigned u = __float_as_uint(f);
  u = u + 0x7FFFu + ((u >> 16) & 1u);   // RTNE
  return (short)(u >> 16);
}

__device__ __forceinline__ f32x4 mfma16(bf16x8 a, bf16x8 b, f32x4 c) {
  return __builtin_amdgcn_mfma_f32_16x16x32_bf16(a, b, c, 0, 0, 0);
}

template<bool MAXOP>
__device__ __forceinline__ float block_reduce(float v, float* sbuf) {
  #pragma unroll
  for (int o = 32; o >= 1; o >>= 1) {
    float t = __shfl_down(v, o);
    v = MAXOP ? fmaxf(v, t) : (v + t);
  }
  int lane = threadIdx.x & 63, w = threadIdx.x >> 6;
  if (lane == 0) sbuf[w] = v;
  __syncthreads();
  float r = sbuf[0];
  #pragma unroll
  for (int i = 1; i < 4; i++) r = MAXOP ? fmaxf(r, sbuf[i]) : (r + sbuf[i]);
  __syncthreads();
  return r;
}

// ---------- mega kernel: all weight transposes + prep + rmsnorm1 in ONE dispatch ----------
struct TransDesc {
  const float* src; short* dst;
  int R, C, tx, perz, base;
  long long srcZ, dstZ;
};
struct TransAll { TransDesc d[10]; };

#define TGRP 1096   // 16*68 + 8 pad dwords

__global__ __launch_bounds__(256) void mega_k(TransAll ta, int transBlocks,
                                              const int* pos_ids, float* ct, float* st,
                                              const float* qb, const float* kb, const float* vb,
                                              float* biasCat, int* counts,
                                              const float* hidden, const float* ln1_w,
                                              short* x1) {
  __shared__ float tile[4 * TGRP];
  __shared__ float sbuf[4];
  const int bid = blockIdx.x;
  const int t = threadIdx.x;
  if (bid < transBlocks) {
    int w = 0;
    #pragma unroll
    for (int i = 1; i < 10; i++) if (bid >= ta.d[i].base) w = i;
    const TransDesc& D = ta.d[w];
    int local = bid - D.base;
    int z = local / D.perz, rem = local - z * D.perz;
    int by = rem / D.tx, bx = rem - by * D.tx;
    const float* src = D.src + (long long)z * D.srcZ;
    short* dst = D.dst + (long long)z * D.dstZ;
    const int r0 = by * 64, c0 = bx * 64;
    const int C = D.C, R = D.R;
    #pragma unroll
    for (int i = 0; i < 4; i++) {
      int idx = t + i * 256;                 // 0..1023 float4s
      int row = idx >> 4, c4 = (idx & 15) * 4;
      f32x4 v = __builtin_nontemporal_load(
          (const f32x4*)&src[(size_t)(r0 + row) * C + c0 + c4]);
      *(f32x4*)&tile[(row >> 4) * TGRP + (row & 15) * 68 + c4] = v;
    }
    __syncthreads();
    const int col = t >> 2, seg = t & 3;
    const float* tp = &tile[seg * TGRP + col];
    short outv[16];
    #pragma unroll
    for (int j = 0; j < 16; j++)
      outv[j] = f2bf(tp[j * 68]);
    short* dp = &dst[(size_t)(c0 + col) * R + r0 + seg * 16];
    *(int4*)dp = *(const int4*)&outv[0];
    *(int4*)(dp + 8) = *(const int4*)&outv[8];
  } else if (bid < transBlocks + 256) {
    int pb = bid - transBlocks;
    if (pb == 0) {
      if (t < 16) counts[t] = 0;             // counts[8] + pos[8]
      for (int j = t; j < 3072; j += 256)
        biasCat[j] = (j < 2048) ? qb[j] : ((j < 2560) ? kb[j - 2048] : vb[j - 2560]);
    }
    int i = pb * 256 + t;                    // rope tables [0, 65536)
    int p = i >> 6, f = i & 63;
    float pos = (float)pos_ids[p];
    float inv = powf(1.0e6f, -(float)f * (1.f / 64.f));
    float a = pos * inv;
    ct[i] = cosf(a); st[i] = sinf(a);
  } else {
    // rmsnorm1 for token row tr (x1 bf16 only)
    int tr = bid - transBlocks - 256;        // [0, 1024)
    const float* xr = hidden + (long long)tr * H_;
    float ss = 0.f;
    for (int i = t; i < H_ / 4; i += 256) {
      float4 v = ((const float4*)xr)[i];
      ss += v.x * v.x + v.y * v.y + v.z * v.z + v.w * v.w;
    }
    ss = block_reduce<false>(ss, sbuf);
    float rs = rsqrtf(ss * (1.f / (float)H_) + 1e-6f);
    for (int i = t; i < H_; i += 256) {
      float xv = xr[i];
      x1[(long long)tr * H_ + i] = f2bf(xv * rs * ln1_w[i]);
    }
  }
}

// ---------- GEMM: A bf16 [M,K], B bf16 [N,K] (K-contig), BK=32, 2-phase dbuf ----------
// DETERMINISM: h2 chain (QKV, scores, PV, O-proj) has NO atomics - split-K
// writes per-chunk partials (EPI 0: C + zc + kc*kstrideC) reduced in fixed
// order by consumers. Only MoE scatter-adds (EPI 4/5) use atomicAdd.
// LDS bank-conflict fix (rule #21 both-sides swizzle): 16B k-slot XORed with
// row bits; staging pre-swizzles the GLOBAL source column.
// EPI 0: C fp32 = alpha*acc, plain store at C + zc + kc*kstrideC (partials)
// EPI 2: C bf16 = acc (in-register full-K accumulation)
// EPI 4: expert: A row = off+m, atomicAdd(C[list[off+m]*ldc+n], scale[off+m]*acc)
// EPI 5: atomicAdd(C[m*ldc+n], scale[m]*acc)
// EPI 6: FUSED gate+up+silu, dense: B-tile = 64 gate rows + 64 up rows; C bf16.
// EPI 7: FUSED, expert-gathered: A row = list[off+m], C row = off+m.
struct GemmP {
  const short* A; long long strideA; int adiv; int lda;
  const short* B; long long strideB; int bdiv; int ldb;
  void* C; long long strideC; long long kstrideC; int cdiv; int ldc;
  const int* e_off; const int* e_cnt;
  const int* list; const float* scale;
  float alpha;
  int M, N, K;
  int cskip, ckb;
  int ksplit, kchunk;
  int upoff;
};

template<int EPI>
__device__ __forceinline__ void gemm_body(const GemmP& p, int bx, int by, int bz,
                                          short* As, short* Bs) {
  constexpr bool FUSED = (EPI == 6 || EPI == 7);
  constexpr bool GATH  = (EPI == 7);
  constexpr int BM = 128, BK = 32;
  const int zo = bz / p.ksplit;
  const int kc = bz - zo * p.ksplit;
  const int m0 = by * BM;
  const int n0 = bx * (FUSED ? 64 : 128);
  if (FUSED && n0 >= p.N) return;

  int off = 0, cnt = p.M;
  if constexpr (EPI == 4 || GATH) {
    off = p.e_off[zo]; cnt = p.e_cnt[zo];
    if (m0 >= cnt) return;
  }
  if (p.cskip && n0 >= m0 + BM) return;
  int kend = p.ckb ? min(m0 + BM, p.K) : p.K;
  const int kbeg = kc * p.kchunk;
  kend = min(kend, kbeg + p.kchunk);
  if (kbeg >= kend) return;

  const short* Ab = p.A + (long long)(zo / p.adiv) * p.strideA;
  const short* Bb = p.B + (long long)(zo / p.bdiv) * p.strideB;

  const int tid = threadIdx.x;
  const int lane = tid & 63, wid = tid >> 6;
  const int wr = wid >> 1, wc = wid & 1;
  const int kg = lane >> 4, li = lane & 15;

  const int srow = tid >> 2;
  const int scol = (((tid & 3) ^ ((tid >> 3) & 3))) * 8;
  const short* aSrc[2];
  const short* bSrc[2];
  #pragma unroll
  for (int c = 0; c < 2; c++) {
    int ra = srow + c * 64;
    int gr;
    if constexpr (GATH)          { int rr = m0 + ra; if (rr >= cnt) rr = cnt - 1; gr = p.list[off + rr]; }
    else if constexpr (EPI == 4) { int rr = m0 + ra; if (rr >= cnt) rr = cnt - 1; gr = off + rr; }
    else                         gr = m0 + ra;
    aSrc[c] = Ab + (long long)gr * p.lda + scol;
    int br = FUSED ? (n0 + srow + (c ? p.upoff : 0)) : (n0 + srow + c * 64);
    bSrc[c] = Bb + (long long)br * p.ldb + scol;
  }

  f32x4 acc[4][4];
  #pragma unroll
  for (int i = 0; i < 4; i++)
    #pragma unroll
    for (int j = 0; j < 4; j++) acc[i][j] = (f32x4){0.f, 0.f, 0.f, 0.f};

  #pragma unroll
  for (int c = 0; c < 2; c++) {
    gload16(aSrc[c] + kbeg, &As[tid * 8 + c * 2048]);
    gload16(bSrc[c] + kbeg, &Bs[tid * 8 + c * 2048]);
  }
  __syncthreads();

  const int kgx = kg ^ ((li >> 1) & 3);
  int brow[4];
  #pragma unroll
  for (int nj = 0; nj < 4; nj++)
    brow[nj] = FUSED ? (((nj & 2) ? 64 : 0) + wc * 32 + (nj & 1) * 16 + li)
                     : (wc * 64 + nj * 16 + li);

  int cur = 0;
  for (int k0 = kbeg; k0 < kend; k0 += BK) {
    const int nk = k0 + BK;
    if (nk < kend) {
      #pragma unroll
      for (int c = 0; c < 2; c++) {
        gload16(aSrc[c] + nk, &As[(cur ^ 1) * 4096 + tid * 8 + c * 2048]);
        gload16(bSrc[c] + nk, &Bs[(cur ^ 1) * 4096 + tid * 8 + c * 2048]);
      }
    }
    bf16x8 av[4], bv[4];
    #pragma unroll
    for (int mi = 0; mi < 4; mi++)
      av[mi] = *(const bf16x8*)&As[cur * 4096 + (wr * 64 + mi * 16 + li) * BK + kgx * 8];
    #pragma unroll
    for (int nj = 0; nj < 4; nj++)
      bv[nj] = *(const bf16x8*)&Bs[cur * 4096 + brow[nj] * BK + kgx * 8];
    #pragma unroll
    for (int mi = 0; mi < 4; mi++)
      #pragma unroll
      for (int nj = 0; nj < 4; nj++)
        acc[mi][nj] = mfma16(av[mi], bv[nj], acc[mi][nj]);
    __syncthreads();
    cur ^= 1;
  }

  const long long zc = (long long)(zo / p.cdiv) * p.strideC;
  if constexpr (FUSED) {
    short* C = (short*)p.C;
    #pragma unroll
    for (int mi = 0; mi < 4; mi++) {
      #pragma unroll
      for (int nj = 0; nj < 2; nj++) {
        #pragma unroll
        for (int r = 0; r < 4; r++) {
          int ml = wr * 64 + mi * 16 + kg * 4 + r;
          int mg = m0 + ml;
          int ng = n0 + wc * 32 + nj * 16 + li;
          float g = acc[mi][nj][r], u = acc[mi][nj + 2][r];
          float gu = g * (1.f / (1.f + __expf(-g))) * u;
          if constexpr (GATH) {
            if (mg < cnt) C[(long long)(off + mg) * p.ldc + ng] = f2bf(gu);
          } else {
            C[(long long)mg * p.ldc + ng] = f2bf(gu);
          }
        }
      }
    }
  } else {
    #pragma unroll
    for (int mi = 0; mi < 4; mi++) {
      #pragma unroll
      for (int nj = 0; nj < 4; nj++) {
        #pragma unroll
        for (int r = 0; r < 4; r++) {
          int ml = wr * 64 + mi * 16 + kg * 4 + r;
          int nl2 = wc * 64 + nj * 16 + li;
          int mg = m0 + ml, ng = n0 + nl2;
          float v = acc[mi][nj][r] * p.alpha;
          if constexpr (EPI == 0) {
            float* C = (float*)p.C + zc + (long long)kc * p.kstrideC;
            C[(long long)mg * p.ldc + ng] = v;
          } else if constexpr (EPI == 2) {
            short* C = (short*)p.C + zc;
            C[(long long)mg * p.ldc + ng] = f2bf(v);
          } else if constexpr (EPI == 4) {
            if (mg < cnt) {
              float* C = (float*)p.C;
              int tok = p.list[off + mg];
              atomicAdd(&C[(long long)tok * p.ldc + ng], p.scale[off + mg] * v);
            }
          } else if constexpr (EPI == 5) {
            float* C = (float*)p.C;
            atomicAdd(&C[(long long)mg * p.ldc + ng], p.scale[mg] * v);
          }
        }
      }
    }
  }
}

template<int EPI>
__global__ __launch_bounds__(256) void gemm_bt(GemmP p) {
  __shared__ __align__(16) short As[2 * 128 * 32];
  __shared__ __align__(16) short Bs[2 * 128 * 32];
  gemm_body<EPI>(p, blockIdx.x, blockIdx.y, blockIdx.z, As, Bs);
}

// gu-dual: grid (22, 8, 12). z<8: expert e=z (EPI7, 22 n-tiles of 64).
// z in [8,12): shared (EPI6), n-tile = (z-8)*22 + x in [0,88). Zero dead blocks.
__global__ __launch_bounds__(256) void gemm_gu_dual(GemmP pe, GemmP ps) {
  __shared__ __align__(16) short As[2 * 128 * 32];
  __shared__ __align__(16) short Bs[2 * 128 * 32];
  int z = blockIdx.z;
  if (z < E_) gemm_body<7>(pe, blockIdx.x, blockIdx.y, z, As, Bs);
  else        gemm_body<6>(ps, (z - E_) * 22 + blockIdx.x, blockIdx.y, 0, As, Bs);
}

// generic dual (down-projections): z < z1 -> p1 (EPI1), else p2 (EPI2).
template<int EPI1, int EPI2>
__global__ __launch_bounds__(256) void gemm_dual(GemmP p1, GemmP p2, int z1) {
  __shared__ __align__(16) short As[2 * 128 * 32];
  __shared__ __align__(16) short Bs[2 * 128 * 32];
  int z = blockIdx.z;
  if (z < z1) gemm_body<EPI1>(p1, blockIdx.x, blockIdx.y, z, As, Bs);
  else        gemm_body<EPI2>(p2, blockIdx.x, blockIdx.y, z - z1, As, Bs);
}

// ---------- aux kernels ----------
// fused RoPE(q,k) + V-transpose reading QKV split-K partials (p0+p1+bias, fixed order)
__global__ __launch_bounds__(256) void rope_fused_k(const float* p0, const float* p1,
                                                    const float* bias, short* qr, short* kr,
                                                    short* vt, const float* ct, const float* st) {
  int i = blockIdx.x * 256 + threadIdx.x;          // [0, 3145728)
  if (i < 2097152) {                               // Q rope
    int t = i >> 11, j = i & 2047;
    int d = j & 127, f = d & 63;
    float c = ct[t * 64 + f], s = st[t * 64 + f];
    long long base = (long long)t * 3072;
    float xv = p0[base + j] + p1[base + j] + bias[j];
    int jo = (d < 64) ? j + 64 : j - 64;
    float ov = p0[base + jo] + p1[base + jo] + bias[jo];
    if (d < 64) ov = -ov;
    qr[i] = f2bf(xv * c + ov * s);
  } else if (i < 2621440) {                        // K rope
    int j = i - 2097152;
    int t = j >> 9, jj = j & 511;
    int d = jj & 127, f = d & 63;
    float c = ct[t * 64 + f], s = st[t * 64 + f];
    long long base = (long long)t * 3072 + 2048;
    float xv = p0[base + jj] + p1[base + jj] + bias[2048 + jj];
    int jo = (d < 64) ? jj + 64 : jj - 64;
    float ov = p0[base + jo] + p1[base + jo] + bias[2048 + jo];
    if (d < 64) ov = -ov;
    kr[j] = f2bf(xv * c + ov * s);
  } else {                                         // V transpose
    int j = i - 2621440;                           // kvh*131072 + d*1024 + s
    int kvh = j >> 17, rem = j & 131071;
    int d = rem >> 10, s_ = rem & 1023;
    long long idx = (long long)s_ * 3072 + 2560 + kvh * 128 + d;
    vt[j] = f2bf(p0[idx] + p1[idx] + bias[2560 + kvh * 128 + d]);
  }
}

// PV split-K partial reduce: attn[r][c] = bf16( sum_{kc=0}^{r>>8} pp[kc][r][c] ).
// Chunk kc covers K in [kc*256,(kc+1)*256); causal bound for row r's m-tile is
// (r&~127)+128, so chunk kc was written iff kc <= r>>8. Fixed order -> deterministic.
__global__ __launch_bounds__(256) void pv_red_k(const float* pp, short* attn) {
  int i = blockIdx.x * 256 + threadIdx.x;          // [0, S_*H_)
  int r = i >> 11;                                 // row (H_=2048)
  int nl = r >> 8;                                 // last live chunk
  float s = pp[i];
  for (int kc = 1; kc <= nl; kc++) s += pp[(size_t)kc * S_ * H_ + i];
  attn[i] = f2bf(s);
}

// rmsnorm2 fused with O-proj partial reduction: h2 = p0+p1+hidden (fixed order),
// writes out=h2, x2=bf16(h2*rs*w), rs2.
__global__ __launch_bounds__(256) void rmsnorm2f_k(const float* p0, const float* p1,
                                                   const float* hid, const float* w,
                                                   short* x2, float* outp, float* rs_out) {
  __shared__ float rowbuf[H_];
  __shared__ float sbuf[4];
  int tr = blockIdx.x;
  long long base = (long long)tr * H_;
  float ss = 0.f;
  for (int i = threadIdx.x; i < H_; i += 256) {
    float hv = p0[base + i] + p1[base + i] + hid[base + i];
    rowbuf[i] = hv;
    ss += hv * hv;
  }
  ss = block_reduce<false>(ss, sbuf);
  float rs = rsqrtf(ss * (1.f / (float)H_) + 1e-6f);
  for (int i = threadIdx.x; i < H_; i += 256) {
    float hv = rowbuf[i];
    outp[base + i] = hv;
    x2[base + i] = f2bf(hv * rs * w[i]);
  }
  if (threadIdx.x == 0) rs_out[tr] = rs;
}

__global__ __launch_bounds__(256) void softmax_k(const float* sc, short* P) {
  __shared__ float sbuf[4];
  long long row = blockIdx.x;                      // h*1024+q
  int q = (int)(row & (S_ - 1));
  const float* sr = sc + row * S_;
  short* pr = P + row * S_;
  int L = q + 1;
  int Lcap = (q & ~127) + 128;                     // PV never reads beyond this
  float mx = -3.4e38f;
  for (int i = threadIdx.x; i < L; i += 256) mx = fmaxf(mx, sr[i]);
  mx = block_reduce<true>(mx, sbuf);
  float s = 0.f;
  for (int i = threadIdx.x; i < L; i += 256) s += __expf(sr[i] - mx);
  s = block_reduce<false>(s, sbuf);
  float inv = 1.f / s;
  for (int i = threadIdx.x; i < Lcap; i += 256) {
    float pv = (i < L) ? __expf(sr[i] - mx) * inv : 0.f;
    pr[i] = f2bf(pv);
  }
}

__global__ void router_k(const float* h2, const float* rs, const float* w2,
                         const float* rw, const float* sgw,
                         int* top_i, float* top_w, float* sg_sig, int* counts) {
  int t = blockIdx.x;
  int l = threadIdx.x;   // 64 threads
  float le[8] = {0, 0, 0, 0, 0, 0, 0, 0};
  float ls = 0.f;
  float r = rs[t];
  for (int k = l; k < H_; k += 64) {
    float xv = h2[(long long)t * H_ + k] * r * w2[k];
    ls += xv * sgw[k];
    const float* rk = rw + k * E_;
    #pragma unroll
    for (int e = 0; e < E_; e++) le[e] += xv * rk[e];
  }
  #pragma unroll
  for (int o = 32; o >= 1; o >>= 1) {
    ls += __shfl_down(ls, o);
    #pragma unroll
    for (int e = 0; e < E_; e++) le[e] += __shfl_down(le[e], o);
  }
  if (l == 0) {
    float m = le[0];
    for (int e = 1; e < E_; e++) m = fmaxf(m, le[e]);
    float pe[8], s = 0.f;
    for (int e = 0; e < E_; e++) { pe[e] = __expf(le[e] - m); s += pe[e]; }
    float inv = 1.f / s;
    for (int e = 0; e < E_; e++) pe[e] *= inv;
    int i1 = 0;
    for (int e = 1; e < E_; e++) if (pe[e] > pe[i1]) i1 = e;
    int i2 = -1;
    for (int e = 0; e < E_; e++) if (e != i1 && (i2 < 0 || pe[e] > pe[i2])) i2 = e;
    top_i[2 * t] = i1; top_i[2 * t + 1] = i2;
    top_w[2 * t] = pe[i1]; top_w[2 * t + 1] = pe[i2];
    sg_sig[t] = 1.f / (1.f + __expf(-ls));
    atomicAdd(&counts[i1], 1); atomicAdd(&counts[i2], 1);
  }
}

__global__ void scan_k(const int* counts, int* offs) {
  if (threadIdx.x == 0 && blockIdx.x == 0) {
    int s = 0;
    for (int e = 0; e < E_; e++) { offs[e] = s; s += counts[e]; }
  }
}

__global__ __launch_bounds__(256) void fill_k(const int* top_i, const float* top_w, const int* offs,
                                              int* pos, int* list, float* pw) {
  int t = blockIdx.x * 256 + threadIdx.x;
  if (t >= S_) return;
  for (int j = 0; j < 2; j++) {
    int e = top_i[2 * t + j];
    int p_ = atomicAdd(&pos[e], 1);
    int slot = offs[e] + p_;
    list[slot] = t; pw[slot] = top_w[2 * t + j];
  }
}

// ---------- host ----------
static GemmP mkp() {
  GemmP p{};
  p.adiv = 1; p.bdiv = 1; p.cdiv = 1; p.alpha = 1.f;
  p.ksplit = 1; p.kchunk = 1 << 30;
  p.upoff = 0; p.kstrideC = 0;
  return p;
}

extern "C" void kernel_launch(void* const* d_in, const int* in_sizes, int n_in,
                              void* d_out, int out_size, void* d_ws, size_t ws_size,
                              hipStream_t stream) {
  const float* hidden   = (const float*)d_in[0];
  const int*   pos_ids  = (const int*)d_in[1];
  const float* ln1_w    = (const float*)d_in[2];
  const float* ln2_w    = (const float*)d_in[3];
  const float* q_w      = (const float*)d_in[4];
  const float* q_b      = (const float*)d_in[5];
  const float* k_w      = (const float*)d_in[6];
  const float* k_b      = (const float*)d_in[7];
  const float* v_w      = (const float*)d_in[8];
  const float* v_b      = (const float*)d_in[9];
  const float* o_w      = (const float*)d_in[10];
  const float* router_w = (const float*)d_in[11];
  const float* e_gate   = (const float*)d_in[12];
  const float* e_up     = (const float*)d_in[13];
  const float* e_down   = (const float*)d_in[14];
  const float* s_gate   = (const float*)d_in[15];
  const float* s_up     = (const float*)d_in[16];
  const float* s_down   = (const float*)d_in[17];
  const float* sg_w     = (const float*)d_in[18];
  float* out = (float*)d_out;

  char* base = (char*)d_ws;
  size_t off_ = 0;
  auto alc = [&](size_t nbytes) -> char* {
    off_ = (off_ + 255) & ~(size_t)255;
    char* p = base + off_;
    off_ += nbytes;
    return p;
  };
  short* qkvT = (short*)alc((size_t)3072 * H_ * 2);
  short* oT   = (short*)alc((size_t)H_ * H_ * 2);
  short* eguT = (short*)alc((size_t)E_ * 2816 * H_ * 2);
  short* edT  = (short*)alc((size_t)E_ * H_ * IM_ * 2);
  short* sguT = (short*)alc((size_t)11264 * H_ * 2);
  short* sdT  = (short*)alc((size_t)H_ * ISH_ * 2);
  short* x1      = (short*)alc((size_t)S_ * H_ * 2);
  float* qkv_p   = (float*)alc((size_t)2 * S_ * 3072 * 4);   // QKV split-K partials
  float* o_part  = (float*)alc((size_t)2 * S_ * H_ * 4);     // O-proj split-K partials
  float* pv_part = (float*)alc((size_t)4 * S_ * H_ * 4);     // PV split-K partials
  float* biasCat = (float*)alc(3072 * 4);
  float* ct      = (float*)alc((size_t)S_ * 64 * 4);
  float* st      = (float*)alc((size_t)S_ * 64 * 4);
  short* qr      = (short*)alc((size_t)S_ * H_ * 2);
  short* kr      = (short*)alc((size_t)S_ * 512 * 2);
  short* vt      = (short*)alc((size_t)S_ * 512 * 2);
  short* attn    = (short*)alc((size_t)S_ * H_ * 2);
  short* x2      = (short*)alc((size_t)S_ * H_ * 2);
  float* rs2     = (float*)alc(S_ * 4);
  int*   top_i   = (int*)alc(2 * S_ * 4);
  float* top_w   = (float*)alc(2 * S_ * 4);
  float* sg_sig  = (float*)alc(S_ * 4);
  int*   counts  = (int*)alc(64);
  int*   pos     = counts + 8;
  int*   offs    = (int*)alc(32);
  int*   list    = (int*)alc(2 * S_ * 4);
  float* pw      = (float*)alc(2 * S_ * 4);
  char*  region  = alc(100663296);   // 96 MiB overlay
  float* scores  = (float*)region;                            // 64 MiB
  short* P       = (short*)(region + 67108864);               // 32 MiB
  short* gu_moeB = (short*)region;                            // reuse after attn
  short* gushB   = (short*)(region + 16777216);

  // 0) mega dispatch: all weight transposes + prep + rmsnorm1
  {
    TransAll ta{};
    int b = 0;
    auto add = [&](int i, const float* s, short* d, int R, int C, int tz,
                   long long sZ, long long dZ) {
      int tx = C / 64, ty = R / 64;
      ta.d[i] = TransDesc{s, d, R, C, tx, tx * ty, b, sZ, dZ};
      b += tx * ty * tz;
    };
    add(0, q_w, qkvT, H_, H_, 1, 0, 0);
    add(1, k_w, qkvT + (size_t)2048 * H_, H_, 512, 1, 0, 0);
    add(2, v_w, qkvT + (size_t)2560 * H_, H_, 512, 1, 0, 0);
    add(3, o_w, oT, H_, H_, 1, 0, 0);
    add(4, e_gate, eguT, H_, IM_, E_, (long long)H_ * IM_, (long long)2816 * H_);
    add(5, e_up, eguT + (size_t)1408 * H_, H_, IM_, E_, (long long)H_ * IM_, (long long)2816 * H_);
    add(6, e_down, edT, IM_, H_, E_, (long long)IM_ * H_, (long long)IM_ * H_);
    add(7, s_gate, sguT, H_, ISH_, 1, 0, 0);
    add(8, s_up, sguT + (size_t)5632 * H_, H_, ISH_, 1, 0, 0);
    add(9, s_down, sdT, ISH_, H_, 1, 0, 0);
    mega_k<<<b + 256 + 1024, 256, 0, stream>>>(ta, b, pos_ids, ct, st, q_b, k_b, v_b,
                                               biasCat, counts, hidden, ln1_w, x1);
  }

  // 2) fused QKV projection: split-K=2 -> partial buffers (no atomics)
  {
    GemmP p = mkp();
    p.A = x1; p.lda = H_;
    p.B = qkvT; p.ldb = H_;
    p.C = qkv_p; p.kstrideC = (long long)S_ * 3072; p.ldc = 3072;
    p.M = S_; p.N = 3072; p.K = H_;
    p.ksplit = 2; p.kchunk = 1024;
    gemm_bt<0><<<dim3(24, 8, 2), 256, 0, stream>>>(p);
  }

  // 3) fused RoPE(q,k) + V transpose, reducing the partials (p0+p1+bias)
  rope_fused_k<<<12288, 256, 0, stream>>>(qkv_p, qkv_p + (size_t)S_ * 3072, biasCat,
                                          qr, kr, vt, ct, st);

  // 4) scores = scale * Q K^T (causal tiles only)
  {
    GemmP p = mkp();
    p.A = qr; p.strideA = HD_; p.lda = H_;
    p.B = kr; p.strideB = HD_; p.bdiv = 4; p.ldb = 512;
    p.C = scores; p.strideC = (long long)S_ * S_; p.ldc = S_;
    p.alpha = 0.08838834764831845f;
    p.M = S_; p.N = S_; p.K = HD_; p.cskip = 1;
    gemm_bt<0><<<dim3(8, 8, NH_), 256, 0, stream>>>(p);
  }
  softmax_k<<<NH_ * S_, 256, 0, stream>>>(scores, P);
  // 5) attn = P @ V: deterministic split-K=4 -> pv_part, then fixed-order reduce
  {
    GemmP p = mkp();
    p.A = P; p.strideA = (long long)S_ * S_; p.lda = S_;
    p.B = vt; p.strideB = (long long)HD_ * S_; p.bdiv = 4; p.ldb = S_;
    p.C = pv_part; p.strideC = HD_; p.kstrideC = (long long)S_ * H_; p.ldc = H_;
    p.M = S_; p.N = HD_; p.K = S_; p.ckb = 1;
    p.ksplit = 4; p.kchunk = 256;
    gemm_bt<0><<<dim3(1, 8, NH_ * 4), 256, 0, stream>>>(p);
  }
  pv_red_k<<<8192, 256, 0, stream>>>(pv_part, attn);
  // 6) O-proj: split-K=2 -> partial buffers (no atomics)
  {
    GemmP p = mkp();
    p.A = attn; p.lda = H_;
    p.B = oT; p.ldb = H_;
    p.C = o_part; p.kstrideC = (long long)S_ * H_; p.ldc = H_;
    p.M = S_; p.N = H_; p.K = H_;
    p.ksplit = 2; p.kchunk = 1024;
    gemm_bt<0><<<dim3(16, 8, 2), 256, 0, stream>>>(p);
  }

  // 7) rmsnorm2 fused with O-partial reduction: out = h2 = p0+p1+hidden;
  //    x2 = bf16(h2*rs*ln2_w); rs2. Deterministic -> stable router top-2.
  rmsnorm2f_k<<<S_, 256, 0, stream>>>(o_part, o_part + (size_t)S_ * H_, hidden,
                                      ln2_w, x2, out, rs2);

  // 8) router / top-2 / gather lists (reads out == h2; counts pre-zeroed in mega_k)
  router_k<<<S_, 64, 0, stream>>>(out, rs2, ln2_w, router_w, sg_w, top_i, top_w, sg_sig, counts);
  scan_k<<<1, 1, 0, stream>>>(counts, offs);
  fill_k<<<4, 256, 0, stream>>>(top_i, top_w, offs, pos, list, pw);

  // 9) MERGED gate+up+silu: expert (z<8, 22 n-tiles) + shared (z 8..11, n-tile
  //    = (z-8)*22+x) -> 2112 blocks, zero dead blocks.
  {
    GemmP pe = mkp();
    pe.A = x2; pe.lda = H_;
    pe.B = eguT; pe.strideB = (long long)2816 * H_; pe.ldb = H_;
    pe.C = gu_moeB; pe.ldc = IM_;
    pe.e_off = offs; pe.e_cnt = counts; pe.list = list;
    pe.M = S_; pe.N = IM_; pe.K = H_;
    pe.upoff = IM_;
    GemmP ps = mkp();
    ps.A = x2; ps.lda = H_;
    ps.B = sguT; ps.ldb = H_;
    ps.C = gushB; ps.ldc = ISH_;
    ps.M = S_; ps.N = ISH_; ps.K = H_;
    ps.upoff = ISH_;
    gemm_gu_dual<<<dim3(22, 8, 12), 256, 0, stream>>>(pe, ps);
  }

  // 10) MERGED down-projections: expert scatter-add (z<16) + shared (z 16..19).
  //     atomicAdd here is rounding-level nondeterminism only (continuous path).
  {
    GemmP pe = mkp();
    pe.A = gu_moeB; pe.lda = IM_;
    pe.B = edT; pe.strideB = (long long)H_ * IM_; pe.ldb = IM_;
    pe.C = out; pe.ldc = H_;
    pe.e_off = offs; pe.e_cnt = counts; pe.list = list; pe.scale = pw;
    pe.M = S_; pe.N = H_; pe.K = IM_;
    pe.ksplit = 2; pe.kchunk = 704;
    GemmP ps = mkp();
    ps.A = gushB; ps.lda = ISH_;
    ps.B = sdT; ps.ldb = ISH_;
    ps.C = out; ps.ldc = H_; ps.scale = sg_sig;
    ps.M = S_; ps.N = H_; ps.K = ISH_;
    ps.ksplit = 4; ps.kchunk = 1408;
    gemm_dual<4, 5><<<dim3(16, 8, E_ * 2 + 4), 256, 0, stream>>>(pe, ps, E_ * 2);
  }
}

// Round 20
// 537.412 us; speedup vs baseline: 1.0449x; 1.0343x over previous
//
#include <hip/hip_runtime.h>
#include <hip/hip_bf16.h>

// ---------- constants ----------
#define S_ 1024
#define H_ 2048
#define NH_ 16
#define KVH_ 4
#define HD_ 128
#define IM_ 1408
#define ISH_ 5632
#define E_ 8

typedef __bf16 bf16x8 __attribute__((ext_vector_type(8)));
typedef float f32x4 __attribute__((ext_vector_type(4)));

typedef unsigned int __attribute__((address_space(1))) as1_u32;
typedef unsigned int __attribute__((address_space(3))) as3_u32;

__device__ __forceinline__ void gload16(const void* g, void* l) {
  __builtin_amdgcn_global_load_lds((const as1_u32*)g, (as3_u32*)l, 16, 0, 0);
}

__device__ __forceinline__ short f2bf(float f) {
  unsigned u = __float_as_uint(f);
  u = u + 0x7FFFu + ((u >> 16) & 1u);   // RTNE
  return (short)(u >> 16);
}

__device__ __forceinline__ f32x4 mfma16(bf16x8 a, bf16x8 b, f32x4 c) {
  return __builtin_amdgcn_mfma_f32_16x16x32_bf16(a, b, c, 0, 0, 0);
}

template<bool MAXOP>
__device__ __forceinline__ float block_reduce(float v, float* sbuf) {
  #pragma unroll
  for (int o = 32; o >= 1; o >>= 1) {
    float t = __shfl_down(v, o);
    v = MAXOP ? fmaxf(v, t) : (v + t);
  }
  int lane = threadIdx.x & 63, w = threadIdx.x >> 6;
  if (lane == 0) sbuf[w] = v;
  __syncthreads();
  float r = sbuf[0];
  #pragma unroll
  for (int i = 1; i < 4; i++) r = MAXOP ? fmaxf(r, sbuf[i]) : (r + sbuf[i]);
  __syncthreads();
  return r;
}

// ---------- transpose v3 body (fp32 LDS tile, conflict-free) ----------
struct TransDesc {
  const float* src; short* dst;
  int R, C, tx, perz, base;
  long long srcZ, dstZ;
};
struct TransAttn { TransDesc d[4]; };
struct TransMoE  { TransDesc d[6]; };

#define TGRP 1096   // 16*68 + 8 pad dwords; tile = 4*TGRP floats = 17536 B

__device__ __forceinline__ void trans_body(const TransDesc& D, int local, float* tile) {
  const int t = threadIdx.x;
  int z = local / D.perz, rem = local - z * D.perz;
  int by = rem / D.tx, bx = rem - by * D.tx;
  const float* src = D.src + (long long)z * D.srcZ;
  short* dst = D.dst + (long long)z * D.dstZ;
  const int r0 = by * 64, c0 = bx * 64;
  const int C = D.C, R = D.R;
  #pragma unroll
  for (int i = 0; i < 4; i++) {
    int idx = t + i * 256;                 // 0..1023 float4s
    int row = idx >> 4, c4 = (idx & 15) * 4;
    f32x4 v = __builtin_nontemporal_load(
        (const f32x4*)&src[(size_t)(r0 + row) * C + c0 + c4]);
    *(f32x4*)&tile[(row >> 4) * TGRP + (row & 15) * 68 + c4] = v;
  }
  __syncthreads();
  const int col = t >> 2, seg = t & 3;
  const float* tp = &tile[seg * TGRP + col];
  short outv[16];
  #pragma unroll
  for (int j = 0; j < 16; j++)
    outv[j] = f2bf(tp[j * 68]);
  short* dp = &dst[(size_t)(c0 + col) * R + r0 + seg * 16];
  *(int4*)dp = *(const int4*)&outv[0];
  *(int4*)(dp + 8) = *(const int4*)&outv[8];
}

// ---------- mega kernel: attn weight transposes + prep + rmsnorm1 ----------
__global__ __launch_bounds__(256) void mega_k(TransAttn ta, int transBlocks,
                                              const int* pos_ids, float* ct, float* st,
                                              const float* qb, const float* kb, const float* vb,
                                              float* biasCat, int* counts,
                                              const float* hidden, const float* ln1_w,
                                              short* x1) {
  __shared__ float tile[4 * TGRP];
  __shared__ float sbuf[4];
  const int bid = blockIdx.x;
  const int t = threadIdx.x;
  if (bid < transBlocks) {
    int w = 0;
    #pragma unroll
    for (int i = 1; i < 4; i++) if (bid >= ta.d[i].base) w = i;
    trans_body(ta.d[w], bid - ta.d[w].base, tile);
  } else if (bid < transBlocks + 256) {
    int pb = bid - transBlocks;
    if (pb == 0) {
      if (t < 16) counts[t] = 0;             // counts[8] + pos[8]
      for (int j = t; j < 3072; j += 256)
        biasCat[j] = (j < 2048) ? qb[j] : ((j < 2560) ? kb[j - 2048] : vb[j - 2560]);
    }
    int i = pb * 256 + t;                    // rope tables [0, 65536)
    int p = i >> 6, f = i & 63;
    float pos = (float)pos_ids[p];
    float inv = powf(1.0e6f, -(float)f * (1.f / 64.f));
    float a = pos * inv;
    ct[i] = cosf(a); st[i] = sinf(a);
  } else {
    // rmsnorm1 for token row tr (x1 bf16 only)
    int tr = bid - transBlocks - 256;        // [0, 1024)
    const float* xr = hidden + (long long)tr * H_;
    float ss = 0.f;
    for (int i = t; i < H_ / 4; i += 256) {
      float4 v = ((const float4*)xr)[i];
      ss += v.x * v.x + v.y * v.y + v.z * v.z + v.w * v.w;
    }
    ss = block_reduce<false>(ss, sbuf);
    float rs = rsqrtf(ss * (1.f / (float)H_) + 1e-6f);
    for (int i = t; i < H_; i += 256) {
      float xv = xr[i];
      x1[(long long)tr * H_ + i] = f2bf(xv * rs * ln1_w[i]);
    }
  }
}

// ---------- GEMM: A bf16 [M,K], B bf16 [N,K] (K-contig), BK=32, 2-phase dbuf ----------
// DETERMINISM: h2 chain (QKV, scores, PV, O-proj) has NO atomics - split-K
// writes per-chunk partials (EPI 0: C + zc + kc*kstrideC) reduced in fixed
// order by consumers. Only MoE scatter-adds (EPI 4/5) use atomicAdd.
// LDS bank-conflict fix (rule #21 both-sides swizzle): 16B k-slot XORed with
// row bits; staging pre-swizzles the GLOBAL source column.
// EPI 0: C fp32 = alpha*acc, plain store at C + zc + kc*kstrideC (partials)
// EPI 2: C bf16 = acc (in-register full-K accumulation)
// EPI 4: expert: A row = off+m, atomicAdd(C[list[off+m]*ldc+n], scale[off+m]*acc)
// EPI 5: atomicAdd(C[m*ldc+n], scale[m]*acc)
// EPI 6: FUSED gate+up+silu, dense: B-tile = 64 gate rows + 64 up rows; C bf16.
// EPI 7: FUSED, expert-gathered: A row = list[off+m], C row = off+m.
struct GemmP {
  const short* A; long long strideA; int adiv; int lda;
  const short* B; long long strideB; int bdiv; int ldb;
  void* C; long long strideC; long long kstrideC; int cdiv; int ldc;
  const int* e_off; const int* e_cnt;
  const int* list; const float* scale;
  float alpha;
  int M, N, K;
  int cskip, ckb;
  int ksplit, kchunk;
  int upoff;
};

template<int EPI>
__device__ __forceinline__ void gemm_body(const GemmP& p, int bx, int by, int bz,
                                          short* As, short* Bs) {
  constexpr bool FUSED = (EPI == 6 || EPI == 7);
  constexpr bool GATH  = (EPI == 7);
  constexpr int BM = 128, BK = 32;
  const int zo = bz / p.ksplit;
  const int kc = bz - zo * p.ksplit;
  const int m0 = by * BM;
  const int n0 = bx * (FUSED ? 64 : 128);
  if (FUSED && n0 >= p.N) return;

  int off = 0, cnt = p.M;
  if constexpr (EPI == 4 || GATH) {
    off = p.e_off[zo]; cnt = p.e_cnt[zo];
    if (m0 >= cnt) return;
  }
  if (p.cskip && n0 >= m0 + BM) return;
  int kend = p.ckb ? min(m0 + BM, p.K) : p.K;
  const int kbeg = kc * p.kchunk;
  kend = min(kend, kbeg + p.kchunk);
  if (kbeg >= kend) return;

  const short* Ab = p.A + (long long)(zo / p.adiv) * p.strideA;
  const short* Bb = p.B + (long long)(zo / p.bdiv) * p.strideB;

  const int tid = threadIdx.x;
  const int lane = tid & 63, wid = tid >> 6;
  const int wr = wid >> 1, wc = wid & 1;
  const int kg = lane >> 4, li = lane & 15;

  const int srow = tid >> 2;
  const int scol = (((tid & 3) ^ ((tid >> 3) & 3))) * 8;
  const short* aSrc[2];
  const short* bSrc[2];
  #pragma unroll
  for (int c = 0; c < 2; c++) {
    int ra = srow + c * 64;
    int gr;
    if constexpr (GATH)          { int rr = m0 + ra; if (rr >= cnt) rr = cnt - 1; gr = p.list[off + rr]; }
    else if constexpr (EPI == 4) { int rr = m0 + ra; if (rr >= cnt) rr = cnt - 1; gr = off + rr; }
    else                         gr = m0 + ra;
    aSrc[c] = Ab + (long long)gr * p.lda + scol;
    int br = FUSED ? (n0 + srow + (c ? p.upoff : 0)) : (n0 + srow + c * 64);
    bSrc[c] = Bb + (long long)br * p.ldb + scol;
  }

  f32x4 acc[4][4];
  #pragma unroll
  for (int i = 0; i < 4; i++)
    #pragma unroll
    for (int j = 0; j < 4; j++) acc[i][j] = (f32x4){0.f, 0.f, 0.f, 0.f};

  #pragma unroll
  for (int c = 0; c < 2; c++) {
    gload16(aSrc[c] + kbeg, &As[tid * 8 + c * 2048]);
    gload16(bSrc[c] + kbeg, &Bs[tid * 8 + c * 2048]);
  }
  __syncthreads();

  const int kgx = kg ^ ((li >> 1) & 3);
  int brow[4];
  #pragma unroll
  for (int nj = 0; nj < 4; nj++)
    brow[nj] = FUSED ? (((nj & 2) ? 64 : 0) + wc * 32 + (nj & 1) * 16 + li)
                     : (wc * 64 + nj * 16 + li);

  int cur = 0;
  for (int k0 = kbeg; k0 < kend; k0 += BK) {
    const int nk = k0 + BK;
    if (nk < kend) {
      #pragma unroll
      for (int c = 0; c < 2; c++) {
        gload16(aSrc[c] + nk, &As[(cur ^ 1) * 4096 + tid * 8 + c * 2048]);
        gload16(bSrc[c] + nk, &Bs[(cur ^ 1) * 4096 + tid * 8 + c * 2048]);
      }
    }
    bf16x8 av[4], bv[4];
    #pragma unroll
    for (int mi = 0; mi < 4; mi++)
      av[mi] = *(const bf16x8*)&As[cur * 4096 + (wr * 64 + mi * 16 + li) * BK + kgx * 8];
    #pragma unroll
    for (int nj = 0; nj < 4; nj++)
      bv[nj] = *(const bf16x8*)&Bs[cur * 4096 + brow[nj] * BK + kgx * 8];
    #pragma unroll
    for (int mi = 0; mi < 4; mi++)
      #pragma unroll
      for (int nj = 0; nj < 4; nj++)
        acc[mi][nj] = mfma16(av[mi], bv[nj], acc[mi][nj]);
    __syncthreads();
    cur ^= 1;
  }

  const long long zc = (long long)(zo / p.cdiv) * p.strideC;
  if constexpr (FUSED) {
    short* C = (short*)p.C;
    #pragma unroll
    for (int mi = 0; mi < 4; mi++) {
      #pragma unroll
      for (int nj = 0; nj < 2; nj++) {
        #pragma unroll
        for (int r = 0; r < 4; r++) {
          int ml = wr * 64 + mi * 16 + kg * 4 + r;
          int mg = m0 + ml;
          int ng = n0 + wc * 32 + nj * 16 + li;
          float g = acc[mi][nj][r], u = acc[mi][nj + 2][r];
          float gu = g * (1.f / (1.f + __expf(-g))) * u;
          if constexpr (GATH) {
            if (mg < cnt) C[(long long)(off + mg) * p.ldc + ng] = f2bf(gu);
          } else {
            C[(long long)mg * p.ldc + ng] = f2bf(gu);
          }
        }
      }
    }
  } else {
    #pragma unroll
    for (int mi = 0; mi < 4; mi++) {
      #pragma unroll
      for (int nj = 0; nj < 4; nj++) {
        #pragma unroll
        for (int r = 0; r < 4; r++) {
          int ml = wr * 64 + mi * 16 + kg * 4 + r;
          int nl2 = wc * 64 + nj * 16 + li;
          int mg = m0 + ml, ng = n0 + nl2;
          float v = acc[mi][nj][r] * p.alpha;
          if constexpr (EPI == 0) {
            float* C = (float*)p.C + zc + (long long)kc * p.kstrideC;
            C[(long long)mg * p.ldc + ng] = v;
          } else if constexpr (EPI == 2) {
            short* C = (short*)p.C + zc;
            C[(long long)mg * p.ldc + ng] = f2bf(v);
          } else if constexpr (EPI == 4) {
            if (mg < cnt) {
              float* C = (float*)p.C;
              int tok = p.list[off + mg];
              atomicAdd(&C[(long long)tok * p.ldc + ng], p.scale[off + mg] * v);
            }
          } else if constexpr (EPI == 5) {
            float* C = (float*)p.C;
            atomicAdd(&C[(long long)mg * p.ldc + ng], p.scale[mg] * v);
          }
        }
      }
    }
  }
}

template<int EPI>
__global__ __launch_bounds__(256) void gemm_bt(GemmP p) {
  __shared__ __align__(16) short As[2 * 128 * 32];
  __shared__ __align__(16) short Bs[2 * 128 * 32];
  gemm_body<EPI>(p, blockIdx.x, blockIdx.y, blockIdx.z, As, Bs);
}

// GEMM + MoE-weight-transpose co-dispatch: z < zsplit runs the GEMM; z >= zsplit
// runs transpose blocks (idx = (z-zsplit)*gx*gy + bx + gx*by, global g = tbase+idx).
// The BW-bound transpose fills HBM idle time under the latency-bound GEMM blocks;
// kernel-boundary serialization guarantees completion before consumers.
template<int EPI>
__global__ __launch_bounds__(256) void gemm_tr(GemmP p, TransMoE tm, int zsplit,
                                               int tbase, int tcount) {
  __shared__ __align__(16) short smem[2 * 128 * 32 * 2];   // 32 KB shared by both paths
  const int bz = blockIdx.z;
  if (bz >= zsplit) {
    int idx = (bz - zsplit) * (gridDim.x * gridDim.y) + blockIdx.x + gridDim.x * blockIdx.y;
    if (idx < tcount) {
      int g = tbase + idx;
      int w = 0;
      #pragma unroll
      for (int i = 1; i < 6; i++) if (g >= tm.d[i].base) w = i;
      trans_body(tm.d[w], g - tm.d[w].base, (float*)smem);
    }
    return;
  }
  gemm_body<EPI>(p, blockIdx.x, blockIdx.y, bz, smem, smem + 2 * 128 * 32);
}

// gu-dual: grid (22, 8, 12). z<8: expert e=z (EPI7, 22 n-tiles of 64).
// z in [8,12): shared (EPI6), n-tile = (z-8)*22 + x in [0,88). Zero dead blocks.
__global__ __launch_bounds__(256) void gemm_gu_dual(GemmP pe, GemmP ps) {
  __shared__ __align__(16) short As[2 * 128 * 32];
  __shared__ __align__(16) short Bs[2 * 128 * 32];
  int z = blockIdx.z;
  if (z < E_) gemm_body<7>(pe, blockIdx.x, blockIdx.y, z, As, Bs);
  else        gemm_body<6>(ps, (z - E_) * 22 + blockIdx.x, blockIdx.y, 0, As, Bs);
}

// generic dual (down-projections): z < z1 -> p1 (EPI1), else p2 (EPI2).
template<int EPI1, int EPI2>
__global__ __launch_bounds__(256) void gemm_dual(GemmP p1, GemmP p2, int z1) {
  __shared__ __align__(16) short As[2 * 128 * 32];
  __shared__ __align__(16) short Bs[2 * 128 * 32];
  int z = blockIdx.z;
  if (z < z1) gemm_body<EPI1>(p1, blockIdx.x, blockIdx.y, z, As, Bs);
  else        gemm_body<EPI2>(p2, blockIdx.x, blockIdx.y, z - z1, As, Bs);
}

// ---------- aux kernels ----------
// fused RoPE(q,k) + V-transpose reading QKV split-K partials (p0+p1+bias, fixed order)
__global__ __launch_bounds__(256) void rope_fused_k(const float* p0, const float* p1,
                                                    const float* bias, short* qr, short* kr,
                                                    short* vt, const float* ct, const float* st) {
  int i = blockIdx.x * 256 + threadIdx.x;          // [0, 3145728)
  if (i < 2097152) {                               // Q rope
    int t = i >> 11, j = i & 2047;
    int d = j & 127, f = d & 63;
    float c = ct[t * 64 + f], s = st[t * 64 + f];
    long long base = (long long)t * 3072;
    float xv = p0[base + j] + p1[base + j] + bias[j];
    int jo = (d < 64) ? j + 64 : j - 64;
    float ov = p0[base + jo] + p1[base + jo] + bias[jo];
    if (d < 64) ov = -ov;
    qr[i] = f2bf(xv * c + ov * s);
  } else if (i < 2621440) {                        // K rope
    int j = i - 2097152;
    int t = j >> 9, jj = j & 511;
    int d = jj & 127, f = d & 63;
    float c = ct[t * 64 + f], s = st[t * 64 + f];
    long long base = (long long)t * 3072 + 2048;
    float xv = p0[base + jj] + p1[base + jj] + bias[2048 + jj];
    int jo = (d < 64) ? jj + 64 : jj - 64;
    float ov = p0[base + jo] + p1[base + jo] + bias[2048 + jo];
    if (d < 64) ov = -ov;
    kr[j] = f2bf(xv * c + ov * s);
  } else {                                         // V transpose
    int j = i - 2621440;                           // kvh*131072 + d*1024 + s
    int kvh = j >> 17, rem = j & 131071;
    int d = rem >> 10, s_ = rem & 1023;
    long long idx = (long long)s_ * 3072 + 2560 + kvh * 128 + d;
    vt[j] = f2bf(p0[idx] + p1[idx] + bias[2560 + kvh * 128 + d]);
  }
}

// PV split-K partial reduce: attn[r][c] = bf16( sum_{kc=0}^{r>>8} pp[kc][r][c] ).
__global__ __launch_bounds__(256) void pv_red_k(const float* pp, short* attn) {
  int i = blockIdx.x * 256 + threadIdx.x;          // [0, S_*H_)
  int r = i >> 11;                                 // row (H_=2048)
  int nl = r >> 8;                                 // last live chunk
  float s = pp[i];
  for (int kc = 1; kc <= nl; kc++) s += pp[(size_t)kc * S_ * H_ + i];
  attn[i] = f2bf(s);
}

// rmsnorm2 fused with O-proj partial reduction: h2 = p0+p1+hidden (fixed order),
// writes out=h2, x2=bf16(h2*rs*w), rs2.
__global__ __launch_bounds__(256) void rmsnorm2f_k(const float* p0, const float* p1,
                                                   const float* hid, const float* w,
                                                   short* x2, float* outp, float* rs_out) {
  __shared__ float rowbuf[H_];
  __shared__ float sbuf[4];
  int tr = blockIdx.x;
  long long base = (long long)tr * H_;
  float ss = 0.f;
  for (int i = threadIdx.x; i < H_; i += 256) {
    float hv = p0[base + i] + p1[base + i] + hid[base + i];
    rowbuf[i] = hv;
    ss += hv * hv;
  }
  ss = block_reduce<false>(ss, sbuf);
  float rs = rsqrtf(ss * (1.f / (float)H_) + 1e-6f);
  for (int i = threadIdx.x; i < H_; i += 256) {
    float hv = rowbuf[i];
    outp[base + i] = hv;
    x2[base + i] = f2bf(hv * rs * w[i]);
  }
  if (threadIdx.x == 0) rs_out[tr] = rs;
}

__global__ __launch_bounds__(256) void softmax_k(const float* sc, short* P) {
  __shared__ float sbuf[4];
  long long row = blockIdx.x;                      // h*1024+q
  int q = (int)(row & (S_ - 1));
  const float* sr = sc + row * S_;
  short* pr = P + row * S_;
  int L = q + 1;
  int Lcap = (q & ~127) + 128;                     // PV never reads beyond this
  float mx = -3.4e38f;
  for (int i = threadIdx.x; i < L; i += 256) mx = fmaxf(mx, sr[i]);
  mx = block_reduce<true>(mx, sbuf);
  float s = 0.f;
  for (int i = threadIdx.x; i < L; i += 256) s += __expf(sr[i] - mx);
  s = block_reduce<false>(s, sbuf);
  float inv = 1.f / s;
  for (int i = threadIdx.x; i < Lcap; i += 256) {
    float pv = (i < L) ? __expf(sr[i] - mx) * inv : 0.f;
    pr[i] = f2bf(pv);
  }
}

__global__ void router_k(const float* h2, const float* rs, const float* w2,
                         const float* rw, const float* sgw,
                         int* top_i, float* top_w, float* sg_sig, int* counts) {
  int t = blockIdx.x;
  int l = threadIdx.x;   // 64 threads
  float le[8] = {0, 0, 0, 0, 0, 0, 0, 0};
  float ls = 0.f;
  float r = rs[t];
  for (int k = l; k < H_; k += 64) {
    float xv = h2[(long long)t * H_ + k] * r * w2[k];
    ls += xv * sgw[k];
    const float* rk = rw + k * E_;
    #pragma unroll
    for (int e = 0; e < E_; e++) le[e] += xv * rk[e];
  }
  #pragma unroll
  for (int o = 32; o >= 1; o >>= 1) {
    ls += __shfl_down(ls, o);
    #pragma unroll
    for (int e = 0; e < E_; e++) le[e] += __shfl_down(le[e], o);
  }
  if (l == 0) {
    float m = le[0];
    for (int e = 1; e < E_; e++) m = fmaxf(m, le[e]);
    float pe[8], s = 0.f;
    for (int e = 0; e < E_; e++) { pe[e] = __expf(le[e] - m); s += pe[e]; }
    float inv = 1.f / s;
    for (int e = 0; e < E_; e++) pe[e] *= inv;
    int i1 = 0;
    for (int e = 1; e < E_; e++) if (pe[e] > pe[i1]) i1 = e;
    int i2 = -1;
    for (int e = 0; e < E_; e++) if (e != i1 && (i2 < 0 || pe[e] > pe[i2])) i2 = e;
    top_i[2 * t] = i1; top_i[2 * t + 1] = i2;
    top_w[2 * t] = pe[i1]; top_w[2 * t + 1] = pe[i2];
    sg_sig[t] = 1.f / (1.f + __expf(-ls));
    atomicAdd(&counts[i1], 1); atomicAdd(&counts[i2], 1);
  }
}

__global__ void scan_k(const int* counts, int* offs) {
  if (threadIdx.x == 0 && blockIdx.x == 0) {
    int s = 0;
    for (int e = 0; e < E_; e++) { offs[e] = s; s += counts[e]; }
  }
}

__global__ __launch_bounds__(256) void fill_k(const int* top_i, const float* top_w, const int* offs,
                                              int* pos, int* list, float* pw) {
  int t = blockIdx.x * 256 + threadIdx.x;
  if (t >= S_) return;
  for (int j = 0; j < 2; j++) {
    int e = top_i[2 * t + j];
    int p_ = atomicAdd(&pos[e], 1);
    int slot = offs[e] + p_;
    list[slot] = t; pw[slot] = top_w[2 * t + j];
  }
}

// ---------- host ----------
static GemmP mkp() {
  GemmP p{};
  p.adiv = 1; p.bdiv = 1; p.cdiv = 1; p.alpha = 1.f;
  p.ksplit = 1; p.kchunk = 1 << 30;
  p.upoff = 0; p.kstrideC = 0;
  return p;
}

extern "C" void kernel_launch(void* const* d_in, const int* in_sizes, int n_in,
                              void* d_out, int out_size, void* d_ws, size_t ws_size,
                              hipStream_t stream) {
  const float* hidden   = (const float*)d_in[0];
  const int*   pos_ids  = (const int*)d_in[1];
  const float* ln1_w    = (const float*)d_in[2];
  const float* ln2_w    = (const float*)d_in[3];
  const float* q_w      = (const float*)d_in[4];
  const float* q_b      = (const float*)d_in[5];
  const float* k_w      = (const float*)d_in[6];
  const float* k_b      = (const float*)d_in[7];
  const float* v_w      = (const float*)d_in[8];
  const float* v_b      = (const float*)d_in[9];
  const float* o_w      = (const float*)d_in[10];
  const float* router_w = (const float*)d_in[11];
  const float* e_gate   = (const float*)d_in[12];
  const float* e_up     = (const float*)d_in[13];
  const float* e_down   = (const float*)d_in[14];
  const float* s_gate   = (const float*)d_in[15];
  const float* s_up     = (const float*)d_in[16];
  const float* s_down   = (const float*)d_in[17];
  const float* sg_w     = (const float*)d_in[18];
  float* out = (float*)d_out;

  char* base = (char*)d_ws;
  size_t off_ = 0;
  auto alc = [&](size_t nbytes) -> char* {
    off_ = (off_ + 255) & ~(size_t)255;
    char* p = base + off_;
    off_ += nbytes;
    return p;
  };
  short* qkvT = (short*)alc((size_t)3072 * H_ * 2);
  short* oT   = (short*)alc((size_t)H_ * H_ * 2);
  short* eguT = (short*)alc((size_t)E_ * 2816 * H_ * 2);
  short* edT  = (short*)alc((size_t)E_ * H_ * IM_ * 2);
  short* sguT = (short*)alc((size_t)11264 * H_ * 2);
  short* sdT  = (short*)alc((size_t)H_ * ISH_ * 2);
  short* x1      = (short*)alc((size_t)S_ * H_ * 2);
  float* qkv_p   = (float*)alc((size_t)2 * S_ * 3072 * 4);   // QKV split-K partials
  float* o_part  = (float*)alc((size_t)2 * S_ * H_ * 4);     // O-proj split-K partials
  float* pv_part = (float*)alc((size_t)4 * S_ * H_ * 4);     // PV split-K partials
  float* biasCat = (float*)alc(3072 * 4);
  float* ct      = (float*)alc((size_t)S_ * 64 * 4);
  float* st      = (float*)alc((size_t)S_ * 64 * 4);
  short* qr      = (short*)alc((size_t)S_ * H_ * 2);
  short* kr      = (short*)alc((size_t)S_ * 512 * 2);
  short* vt      = (short*)alc((size_t)S_ * 512 * 2);
  short* attn    = (short*)alc((size_t)S_ * H_ * 2);
  short* x2      = (short*)alc((size_t)S_ * H_ * 2);
  float* rs2     = (float*)alc(S_ * 4);
  int*   top_i   = (int*)alc(2 * S_ * 4);
  float* top_w   = (float*)alc(2 * S_ * 4);
  float* sg_sig  = (float*)alc(S_ * 4);
  int*   counts  = (int*)alc(64);
  int*   pos     = counts + 8;
  int*   offs    = (int*)alc(32);
  int*   list    = (int*)alc(2 * S_ * 4);
  float* pw      = (float*)alc(2 * S_ * 4);
  char*  region  = alc(100663296);   // 96 MiB overlay
  float* scores  = (float*)region;                            // 64 MiB
  short* P       = (short*)(region + 67108864);               // 32 MiB
  short* gu_moeB = (short*)region;                            // reuse after attn
  short* gushB   = (short*)(region + 16777216);

  // ---- MoE weight transpose descriptors (co-dispatched with attn GEMMs) ----
  TransMoE tm{};
  int tb = 0;
  {
    auto addm = [&](int i, const float* s, short* d, int R, int C, int tz,
                    long long sZ, long long dZ) {
      int tx = C / 64, ty = R / 64;
      tm.d[i] = TransDesc{s, d, R, C, tx, tx * ty, tb, sZ, dZ};
      tb += tx * ty * tz;
    };
    addm(0, e_gate, eguT, H_, IM_, E_, (long long)H_ * IM_, (long long)2816 * H_);
    addm(1, e_up, eguT + (size_t)1408 * H_, H_, IM_, E_, (long long)H_ * IM_, (long long)2816 * H_);
    addm(2, e_down, edT, IM_, H_, E_, (long long)IM_ * H_, (long long)IM_ * H_);
    addm(3, s_gate, sguT, H_, ISH_, 1, 0, 0);
    addm(4, s_up, sguT + (size_t)5632 * H_, H_, ISH_, 1, 0, 0);
    addm(5, s_down, sdT, ISH_, H_, 1, 0, 0);
    // tb = 25344 total
  }
  const int T_QKV = 12096;   // 63 slices x 192
  const int T_SC  = 6528;    // 102 slices x 64
  const int T_O   = tb - T_QKV - T_SC;   // 6720 -> 53 slices x 128 (64 culled)

  // 0) mega dispatch: attn weight transposes (qkv,o) + prep + rmsnorm1
  {
    TransAttn ta{};
    int b = 0;
    auto add = [&](int i, const float* s, short* d, int R, int C) {
      int tx = C / 64, ty = R / 64;
      ta.d[i] = TransDesc{s, d, R, C, tx, tx * ty, b, 0, 0};
      b += tx * ty;
    };
    add(0, q_w, qkvT, H_, H_);
    add(1, k_w, qkvT + (size_t)2048 * H_, H_, 512);
    add(2, v_w, qkvT + (size_t)2560 * H_, H_, 512);
    add(3, o_w, oT, H_, H_);
    mega_k<<<b + 256 + 1024, 256, 0, stream>>>(ta, b, pos_ids, ct, st, q_b, k_b, v_b,
                                               biasCat, counts, hidden, ln1_w, x1);
  }

  // 2) fused QKV projection (split-K=2 partials) + MoE transpose slices
  {
    GemmP p = mkp();
    p.A = x1; p.lda = H_;
    p.B = qkvT; p.ldb = H_;
    p.C = qkv_p; p.kstrideC = (long long)S_ * 3072; p.ldc = 3072;
    p.M = S_; p.N = 3072; p.K = H_;
    p.ksplit = 2; p.kchunk = 1024;
    gemm_tr<0><<<dim3(24, 8, 2 + 63), 256, 0, stream>>>(p, tm, 2, 0, T_QKV);
  }

  // 3) fused RoPE(q,k) + V transpose, reducing the partials (p0+p1+bias)
  rope_fused_k<<<12288, 256, 0, stream>>>(qkv_p, qkv_p + (size_t)S_ * 3072, biasCat,
                                          qr, kr, vt, ct, st);

  // 4) scores = scale * Q K^T (causal tiles) + MoE transpose slices
  {
    GemmP p = mkp();
    p.A = qr; p.strideA = HD_; p.lda = H_;
    p.B = kr; p.strideB = HD_; p.bdiv = 4; p.ldb = 512;
    p.C = scores; p.strideC = (long long)S_ * S_; p.ldc = S_;
    p.alpha = 0.08838834764831845f;
    p.M = S_; p.N = S_; p.K = HD_; p.cskip = 1;
    gemm_tr<0><<<dim3(8, 8, NH_ + 102), 256, 0, stream>>>(p, tm, NH_, T_QKV, T_SC);
  }
  softmax_k<<<NH_ * S_, 256, 0, stream>>>(scores, P);
  // 5) attn = P @ V: deterministic split-K=4 -> pv_part, then fixed-order reduce
  {
    GemmP p = mkp();
    p.A = P; p.strideA = (long long)S_ * S_; p.lda = S_;
    p.B = vt; p.strideB = (long long)HD_ * S_; p.bdiv = 4; p.ldb = S_;
    p.C = pv_part; p.strideC = HD_; p.kstrideC = (long long)S_ * H_; p.ldc = H_;
    p.M = S_; p.N = HD_; p.K = S_; p.ckb = 1;
    p.ksplit = 4; p.kchunk = 256;
    gemm_bt<0><<<dim3(1, 8, NH_ * 4), 256, 0, stream>>>(p);
  }
  pv_red_k<<<8192, 256, 0, stream>>>(pv_part, attn);
  // 6) O-proj (split-K=2 partials) + remaining MoE transpose slices
  {
    GemmP p = mkp();
    p.A = attn; p.lda = H_;
    p.B = oT; p.ldb = H_;
    p.C = o_part; p.kstrideC = (long long)S_ * H_; p.ldc = H_;
    p.M = S_; p.N = H_; p.K = H_;
    p.ksplit = 2; p.kchunk = 1024;
    gemm_tr<0><<<dim3(16, 8, 2 + 53), 256, 0, stream>>>(p, tm, 2, T_QKV + T_SC, T_O);
  }

  // 7) rmsnorm2 fused with O-partial reduction: out = h2 = p0+p1+hidden;
  //    x2 = bf16(h2*rs*ln2_w); rs2. Deterministic -> stable router top-2.
  rmsnorm2f_k<<<S_, 256, 0, stream>>>(o_part, o_part + (size_t)S_ * H_, hidden,
                                      ln2_w, x2, out, rs2);

  // 8) router / top-2 / gather lists (reads out == h2; counts pre-zeroed in mega_k)
  router_k<<<S_, 64, 0, stream>>>(out, rs2, ln2_w, router_w, sg_w, top_i, top_w, sg_sig, counts);
  scan_k<<<1, 1, 0, stream>>>(counts, offs);
  fill_k<<<4, 256, 0, stream>>>(top_i, top_w, offs, pos, list, pw);

  // 9) MERGED gate+up+silu: expert (z<8, 22 n-tiles) + shared (z 8..11, n-tile
  //    = (z-8)*22+x) -> 2112 blocks, zero dead blocks.
  {
    GemmP pe = mkp();
    pe.A = x2; pe.lda = H_;
    pe.B = eguT; pe.strideB = (long long)2816 * H_; pe.ldb = H_;
    pe.C = gu_moeB; pe.ldc = IM_;
    pe.e_off = offs; pe.e_cnt = counts; pe.list = list;
    pe.M = S_; pe.N = IM_; pe.K = H_;
    pe.upoff = IM_;
    GemmP ps = mkp();
    ps.A = x2; ps.lda = H_;
    ps.B = sguT; ps.ldb = H_;
    ps.C = gushB; ps.ldc = ISH_;
    ps.M = S_; ps.N = ISH_; ps.K = H_;
    ps.upoff = ISH_;
    gemm_gu_dual<<<dim3(22, 8, 12), 256, 0, stream>>>(pe, ps);
  }

  // 10) MERGED down-projections: expert scatter-add (z<16) + shared (z 16..19).
  //     atomicAdd here is rounding-level nondeterminism only (continuous path).
  {
    GemmP pe = mkp();
    pe.A = gu_moeB; pe.lda = IM_;
    pe.B = edT; pe.strideB = (long long)H_ * IM_; pe.ldb = IM_;
    pe.C = out; pe.ldc = H_;
    pe.e_off = offs; pe.e_cnt = counts; pe.list = list; pe.scale = pw;
    pe.M = S_; pe.N = H_; pe.K = IM_;
    pe.ksplit = 2; pe.kchunk = 704;
    GemmP ps = mkp();
    ps.A = gushB; ps.lda = ISH_;
    ps.B = sdT; ps.ldb = ISH_;
    ps.C = out; ps.ldc = H_; ps.scale = sg_sig;
    ps.M = S_; ps.N = H_; ps.K = ISH_;
    ps.ksplit = 4; ps.kchunk = 1408;
    gemm_dual<4, 5><<<dim3(16, 8, E_ * 2 + 4), 256, 0, stream>>>(pe, ps, E_ * 2);
  }
}

// Round 21
// 520.583 us; speedup vs baseline: 1.0787x; 1.0323x over previous
//
#include <hip/hip_runtime.h>
#include <hip/hip_bf16.h>

// ---------- constants ----------
#define S_ 1024
#define H_ 2048
#define NH_ 16
#define KVH_ 4
#define HD_ 128
#define IM_ 1408
#define ISH_ 5632
#define E_ 8

typedef __bf16 bf16x8 __attribute__((ext_vector_type(8)));
typedef float f32x4 __attribute__((ext_vector_type(4)));

typedef unsigned int __attribute__((address_space(1))) as1_u32;
typedef unsigned int __attribute__((address_space(3))) as3_u32;

__device__ __forceinline__ void gload16(const void* g, void* l) {
  __builtin_amdgcn_global_load_lds((const as1_u32*)g, (as3_u32*)l, 16, 0, 0);
}

__device__ __forceinline__ short f2bf(float f) {
  unsigned u = __float_as_uint(f);
  u = u + 0x7FFFu + ((u >> 16) & 1u);   // RTNE
  return (short)(u >> 16);
}

__device__ __forceinline__ float bf2f(short s) {
  return __uint_as_float(((unsigned)(unsigned short)s) << 16);
}

__device__ __forceinline__ f32x4 mfma16(bf16x8 a, bf16x8 b, f32x4 c) {
  return __builtin_amdgcn_mfma_f32_16x16x32_bf16(a, b, c, 0, 0, 0);
}

template<bool MAXOP>
__device__ __forceinline__ float block_reduce(float v, float* sbuf) {
  #pragma unroll
  for (int o = 32; o >= 1; o >>= 1) {
    float t = __shfl_down(v, o);
    v = MAXOP ? fmaxf(v, t) : (v + t);
  }
  int lane = threadIdx.x & 63, w = threadIdx.x >> 6;
  if (lane == 0) sbuf[w] = v;
  __syncthreads();
  float r = sbuf[0];
  #pragma unroll
  for (int i = 1; i < 4; i++) r = MAXOP ? fmaxf(r, sbuf[i]) : (r + sbuf[i]);
  __syncthreads();
  return r;
}

// ---------- transpose v3 body (fp32 LDS tile, conflict-free) ----------
struct TransDesc {
  const float* src; short* dst;
  int R, C, tx, perz, base;
  long long srcZ, dstZ;
};
struct TransAttn { TransDesc d[4]; };
struct TransMoE  { TransDesc d[6]; };

#define TGRP 1096   // 16*68 + 8 pad dwords; tile = 4*TGRP floats = 17536 B

__device__ __forceinline__ void trans_body(const TransDesc& D, int local, float* tile) {
  const int t = threadIdx.x;
  int z = local / D.perz, rem = local - z * D.perz;
  int by = rem / D.tx, bx = rem - by * D.tx;
  const float* src = D.src + (long long)z * D.srcZ;
  short* dst = D.dst + (long long)z * D.dstZ;
  const int r0 = by * 64, c0 = bx * 64;
  const int C = D.C, R = D.R;
  #pragma unroll
  for (int i = 0; i < 4; i++) {
    int idx = t + i * 256;                 // 0..1023 float4s
    int row = idx >> 4, c4 = (idx & 15) * 4;
    f32x4 v = __builtin_nontemporal_load(
        (const f32x4*)&src[(size_t)(r0 + row) * C + c0 + c4]);
    *(f32x4*)&tile[(row >> 4) * TGRP + (row & 15) * 68 + c4] = v;
  }
  __syncthreads();
  const int col = t >> 2, seg = t & 3;
  const float* tp = &tile[seg * TGRP + col];
  short outv[16];
  #pragma unroll
  for (int j = 0; j < 16; j++)
    outv[j] = f2bf(tp[j * 68]);
  short* dp = &dst[(size_t)(c0 + col) * R + r0 + seg * 16];
  *(int4*)dp = *(const int4*)&outv[0];
  *(int4*)(dp + 8) = *(const int4*)&outv[8];
}

// ---------- mega kernel: attn weight transposes + prep + rmsnorm1 ----------
__global__ __launch_bounds__(256) void mega_k(TransAttn ta, int transBlocks,
                                              const int* pos_ids, float* ct, float* st,
                                              const float* qb, const float* kb, const float* vb,
                                              float* biasCat, int* counts,
                                              const float* hidden, const float* ln1_w,
                                              short* x1) {
  __shared__ float tile[4 * TGRP];
  __shared__ float sbuf[4];
  const int bid = blockIdx.x;
  const int t = threadIdx.x;
  if (bid < transBlocks) {
    int w = 0;
    #pragma unroll
    for (int i = 1; i < 4; i++) if (bid >= ta.d[i].base) w = i;
    trans_body(ta.d[w], bid - ta.d[w].base, tile);
  } else if (bid < transBlocks + 256) {
    int pb = bid - transBlocks;
    if (pb == 0) {
      if (t < 16) counts[t] = 0;             // counts[8] + pos[8]
      for (int j = t; j < 3072; j += 256)
        biasCat[j] = (j < 2048) ? qb[j] : ((j < 2560) ? kb[j - 2048] : vb[j - 2560]);
    }
    int i = pb * 256 + t;                    // rope tables [0, 65536)
    int p = i >> 6, f = i & 63;
    float pos = (float)pos_ids[p];
    float inv = powf(1.0e6f, -(float)f * (1.f / 64.f));
    float a = pos * inv;
    ct[i] = cosf(a); st[i] = sinf(a);
  } else {
    // rmsnorm1 for token row tr (x1 bf16 only)
    int tr = bid - transBlocks - 256;        // [0, 1024)
    const float* xr = hidden + (long long)tr * H_;
    float ss = 0.f;
    for (int i = t; i < H_ / 4; i += 256) {
      float4 v = ((const float4*)xr)[i];
      ss += v.x * v.x + v.y * v.y + v.z * v.z + v.w * v.w;
    }
    ss = block_reduce<false>(ss, sbuf);
    float rs = rsqrtf(ss * (1.f / (float)H_) + 1e-6f);
    for (int i = t; i < H_; i += 256) {
      float xv = xr[i];
      x1[(long long)tr * H_ + i] = f2bf(xv * rs * ln1_w[i]);
    }
  }
}

// ---------- GEMM: A bf16 [M,K], B bf16 [N,K] (K-contig), BK=32, 2-phase dbuf ----------
// DETERMINISM: h2 chain (QKV, scores, PV, O-proj) has NO atomics - split-K
// writes per-chunk partials (EPI 0: C + zc + kc*kstrideC) reduced in fixed
// order by consumers. Only MoE scatter-adds (EPI 4/5) use atomicAdd.
// LDS bank-conflict fix (rule #21 both-sides swizzle): 16B k-slot XORed with
// row bits; staging pre-swizzles the GLOBAL source column.
// EPI 0: C fp32 = alpha*acc, plain store at C + zc + kc*kstrideC (partials)
// EPI 2: C bf16 = alpha*acc (in-register full-K accumulation)
// EPI 4: expert: A row = off+m, atomicAdd(C[list[off+m]*ldc+n], scale[off+m]*acc)
// EPI 5: atomicAdd(C[m*ldc+n], scale[m]*acc)
// EPI 6: FUSED gate+up+silu, dense: B-tile = 64 gate rows + 64 up rows; C bf16.
// EPI 7: FUSED, expert-gathered: A row = list[off+m], C row = off+m.
struct GemmP {
  const short* A; long long strideA; int adiv; int lda;
  const short* B; long long strideB; int bdiv; int ldb;
  void* C; long long strideC; long long kstrideC; int cdiv; int ldc;
  const int* e_off; const int* e_cnt;
  const int* list; const float* scale;
  float alpha;
  int M, N, K;
  int cskip, ckb;
  int ksplit, kchunk;
  int upoff;
};

template<int EPI>
__device__ __forceinline__ void gemm_body(const GemmP& p, int bx, int by, int bz,
                                          short* As, short* Bs) {
  constexpr bool FUSED = (EPI == 6 || EPI == 7);
  constexpr bool GATH  = (EPI == 7);
  constexpr int BM = 128, BK = 32;
  const int zo = bz / p.ksplit;
  const int kc = bz - zo * p.ksplit;
  const int m0 = by * BM;
  const int n0 = bx * (FUSED ? 64 : 128);
  if (FUSED && n0 >= p.N) return;

  int off = 0, cnt = p.M;
  if constexpr (EPI == 4 || GATH) {
    off = p.e_off[zo]; cnt = p.e_cnt[zo];
    if (m0 >= cnt) return;
  }
  if (p.cskip && n0 >= m0 + BM) return;
  int kend = p.ckb ? min(m0 + BM, p.K) : p.K;
  const int kbeg = kc * p.kchunk;
  kend = min(kend, kbeg + p.kchunk);
  if (kbeg >= kend) return;

  const short* Ab = p.A + (long long)(zo / p.adiv) * p.strideA;
  const short* Bb = p.B + (long long)(zo / p.bdiv) * p.strideB;

  const int tid = threadIdx.x;
  const int lane = tid & 63, wid = tid >> 6;
  const int wr = wid >> 1, wc = wid & 1;
  const int kg = lane >> 4, li = lane & 15;

  const int srow = tid >> 2;
  const int scol = (((tid & 3) ^ ((tid >> 3) & 3))) * 8;
  const short* aSrc[2];
  const short* bSrc[2];
  #pragma unroll
  for (int c = 0; c < 2; c++) {
    int ra = srow + c * 64;
    int gr;
    if constexpr (GATH)          { int rr = m0 + ra; if (rr >= cnt) rr = cnt - 1; gr = p.list[off + rr]; }
    else if constexpr (EPI == 4) { int rr = m0 + ra; if (rr >= cnt) rr = cnt - 1; gr = off + rr; }
    else                         gr = m0 + ra;
    aSrc[c] = Ab + (long long)gr * p.lda + scol;
    int br = FUSED ? (n0 + srow + (c ? p.upoff : 0)) : (n0 + srow + c * 64);
    bSrc[c] = Bb + (long long)br * p.ldb + scol;
  }

  f32x4 acc[4][4];
  #pragma unroll
  for (int i = 0; i < 4; i++)
    #pragma unroll
    for (int j = 0; j < 4; j++) acc[i][j] = (f32x4){0.f, 0.f, 0.f, 0.f};

  #pragma unroll
  for (int c = 0; c < 2; c++) {
    gload16(aSrc[c] + kbeg, &As[tid * 8 + c * 2048]);
    gload16(bSrc[c] + kbeg, &Bs[tid * 8 + c * 2048]);
  }
  __syncthreads();

  const int kgx = kg ^ ((li >> 1) & 3);
  int brow[4];
  #pragma unroll
  for (int nj = 0; nj < 4; nj++)
    brow[nj] = FUSED ? (((nj & 2) ? 64 : 0) + wc * 32 + (nj & 1) * 16 + li)
                     : (wc * 64 + nj * 16 + li);

  int cur = 0;
  for (int k0 = kbeg; k0 < kend; k0 += BK) {
    const int nk = k0 + BK;
    if (nk < kend) {
      #pragma unroll
      for (int c = 0; c < 2; c++) {
        gload16(aSrc[c] + nk, &As[(cur ^ 1) * 4096 + tid * 8 + c * 2048]);
        gload16(bSrc[c] + nk, &Bs[(cur ^ 1) * 4096 + tid * 8 + c * 2048]);
      }
    }
    bf16x8 av[4], bv[4];
    #pragma unroll
    for (int mi = 0; mi < 4; mi++)
      av[mi] = *(const bf16x8*)&As[cur * 4096 + (wr * 64 + mi * 16 + li) * BK + kgx * 8];
    #pragma unroll
    for (int nj = 0; nj < 4; nj++)
      bv[nj] = *(const bf16x8*)&Bs[cur * 4096 + brow[nj] * BK + kgx * 8];
    #pragma unroll
    for (int mi = 0; mi < 4; mi++)
      #pragma unroll
      for (int nj = 0; nj < 4; nj++)
        acc[mi][nj] = mfma16(av[mi], bv[nj], acc[mi][nj]);
    __syncthreads();
    cur ^= 1;
  }

  const long long zc = (long long)(zo / p.cdiv) * p.strideC;
  if constexpr (FUSED) {
    short* C = (short*)p.C;
    #pragma unroll
    for (int mi = 0; mi < 4; mi++) {
      #pragma unroll
      for (int nj = 0; nj < 2; nj++) {
        #pragma unroll
        for (int r = 0; r < 4; r++) {
          int ml = wr * 64 + mi * 16 + kg * 4 + r;
          int mg = m0 + ml;
          int ng = n0 + wc * 32 + nj * 16 + li;
          float g = acc[mi][nj][r], u = acc[mi][nj + 2][r];
          float gu = g * (1.f / (1.f + __expf(-g))) * u;
          if constexpr (GATH) {
            if (mg < cnt) C[(long long)(off + mg) * p.ldc + ng] = f2bf(gu);
          } else {
            C[(long long)mg * p.ldc + ng] = f2bf(gu);
          }
        }
      }
    }
  } else {
    #pragma unroll
    for (int mi = 0; mi < 4; mi++) {
      #pragma unroll
      for (int nj = 0; nj < 4; nj++) {
        #pragma unroll
        for (int r = 0; r < 4; r++) {
          int ml = wr * 64 + mi * 16 + kg * 4 + r;
          int nl2 = wc * 64 + nj * 16 + li;
          int mg = m0 + ml, ng = n0 + nl2;
          float v = acc[mi][nj][r] * p.alpha;
          if constexpr (EPI == 0) {
            float* C = (float*)p.C + zc + (long long)kc * p.kstrideC;
            C[(long long)mg * p.ldc + ng] = v;
          } else if constexpr (EPI == 2) {
            short* C = (short*)p.C + zc;
            C[(long long)mg * p.ldc + ng] = f2bf(v);
          } else if constexpr (EPI == 4) {
            if (mg < cnt) {
              float* C = (float*)p.C;
              int tok = p.list[off + mg];
              atomicAdd(&C[(long long)tok * p.ldc + ng], p.scale[off + mg] * v);
            }
          } else if constexpr (EPI == 5) {
            float* C = (float*)p.C;
            atomicAdd(&C[(long long)mg * p.ldc + ng], p.scale[mg] * v);
          }
        }
      }
    }
  }
}

template<int EPI>
__global__ __launch_bounds__(256) void gemm_bt(GemmP p) {
  __shared__ __align__(16) short As[2 * 128 * 32];
  __shared__ __align__(16) short Bs[2 * 128 * 32];
  gemm_body<EPI>(p, blockIdx.x, blockIdx.y, blockIdx.z, As, Bs);
}

// GEMM + MoE-weight-transpose co-dispatch: z < zsplit runs the GEMM; z >= zsplit
// runs transpose blocks. The BW-bound transpose fills HBM idle time under the
// latency-bound GEMM blocks; kernel-boundary serialization guarantees order.
template<int EPI>
__global__ __launch_bounds__(256) void gemm_tr(GemmP p, TransMoE tm, int zsplit,
                                               int tbase, int tcount) {
  __shared__ __align__(16) short smem[2 * 128 * 32 * 2];   // 32 KB shared by both paths
  const int bz = blockIdx.z;
  if (bz >= zsplit) {
    int idx = (bz - zsplit) * (gridDim.x * gridDim.y) + blockIdx.x + gridDim.x * blockIdx.y;
    if (idx < tcount) {
      int g = tbase + idx;
      int w = 0;
      #pragma unroll
      for (int i = 1; i < 6; i++) if (g >= tm.d[i].base) w = i;
      trans_body(tm.d[w], g - tm.d[w].base, (float*)smem);
    }
    return;
  }
  gemm_body<EPI>(p, blockIdx.x, blockIdx.y, bz, smem, smem + 2 * 128 * 32);
}

// gu-dual: grid (22, 8, 12). z<8: expert e=z (EPI7, 22 n-tiles of 64).
// z in [8,12): shared (EPI6), n-tile = (z-8)*22 + x in [0,88). Zero dead blocks.
__global__ __launch_bounds__(256) void gemm_gu_dual(GemmP pe, GemmP ps) {
  __shared__ __align__(16) short As[2 * 128 * 32];
  __shared__ __align__(16) short Bs[2 * 128 * 32];
  int z = blockIdx.z;
  if (z < E_) gemm_body<7>(pe, blockIdx.x, blockIdx.y, z, As, Bs);
  else        gemm_body<6>(ps, (z - E_) * 22 + blockIdx.x, blockIdx.y, 0, As, Bs);
}

// generic dual (down-projections): z < z1 -> p1 (EPI1), else p2 (EPI2).
template<int EPI1, int EPI2>
__global__ __launch_bounds__(256) void gemm_dual(GemmP p1, GemmP p2, int z1) {
  __shared__ __align__(16) short As[2 * 128 * 32];
  __shared__ __align__(16) short Bs[2 * 128 * 32];
  int z = blockIdx.z;
  if (z < z1) gemm_body<EPI1>(p1, blockIdx.x, blockIdx.y, z, As, Bs);
  else        gemm_body<EPI2>(p2, blockIdx.x, blockIdx.y, z - z1, As, Bs);
}

// ---------- aux kernels ----------
// fused RoPE(q,k) + V-transpose reading QKV split-K partials (p0+p1+bias, fixed order)
__global__ __launch_bounds__(256) void rope_fused_k(const float* p0, const float* p1,
                                                    const float* bias, short* qr, short* kr,
                                                    short* vt, const float* ct, const float* st) {
  int i = blockIdx.x * 256 + threadIdx.x;          // [0, 3145728)
  if (i < 2097152) {                               // Q rope
    int t = i >> 11, j = i & 2047;
    int d = j & 127, f = d & 63;
    float c = ct[t * 64 + f], s = st[t * 64 + f];
    long long base = (long long)t * 3072;
    float xv = p0[base + j] + p1[base + j] + bias[j];
    int jo = (d < 64) ? j + 64 : j - 64;
    float ov = p0[base + jo] + p1[base + jo] + bias[jo];
    if (d < 64) ov = -ov;
    qr[i] = f2bf(xv * c + ov * s);
  } else if (i < 2621440) {                        // K rope
    int j = i - 2097152;
    int t = j >> 9, jj = j & 511;
    int d = jj & 127, f = d & 63;
    float c = ct[t * 64 + f], s = st[t * 64 + f];
    long long base = (long long)t * 3072 + 2048;
    float xv = p0[base + jj] + p1[base + jj] + bias[2048 + jj];
    int jo = (d < 64) ? jj + 64 : jj - 64;
    float ov = p0[base + jo] + p1[base + jo] + bias[2048 + jo];
    if (d < 64) ov = -ov;
    kr[j] = f2bf(xv * c + ov * s);
  } else {                                         // V transpose
    int j = i - 2621440;                           // kvh*131072 + d*1024 + s
    int kvh = j >> 17, rem = j & 131071;
    int d = rem >> 10, s_ = rem & 1023;
    long long idx = (long long)s_ * 3072 + 2560 + kvh * 128 + d;
    vt[j] = f2bf(p0[idx] + p1[idx] + bias[2560 + kvh * 128 + d]);
  }
}

// PV split-K partial reduce: attn[r][c] = bf16( sum_{kc=0}^{r>>8} pp[kc][r][c] ).
__global__ __launch_bounds__(256) void pv_red_k(const float* pp, short* attn) {
  int i = blockIdx.x * 256 + threadIdx.x;          // [0, S_*H_)
  int r = i >> 11;                                 // row (H_=2048)
  int nl = r >> 8;                                 // last live chunk
  float s = pp[i];
  for (int kc = 1; kc <= nl; kc++) s += pp[(size_t)kc * S_ * H_ + i];
  attn[i] = f2bf(s);
}

// rmsnorm2 fused with O-proj partial reduction: h2 = p0+p1+hidden (fixed order),
// writes out=h2, x2=bf16(h2*rs*w), rs2.
__global__ __launch_bounds__(256) void rmsnorm2f_k(const float* p0, const float* p1,
                                                   const float* hid, const float* w,
                                                   short* x2, float* outp, float* rs_out) {
  __shared__ float rowbuf[H_];
  __shared__ float sbuf[4];
  int tr = blockIdx.x;
  long long base = (long long)tr * H_;
  float ss = 0.f;
  for (int i = threadIdx.x; i < H_; i += 256) {
    float hv = p0[base + i] + p1[base + i] + hid[base + i];
    rowbuf[i] = hv;
    ss += hv * hv;
  }
  ss = block_reduce<false>(ss, sbuf);
  float rs = rsqrtf(ss * (1.f / (float)H_) + 1e-6f);
  for (int i = threadIdx.x; i < H_; i += 256) {
    float hv = rowbuf[i];
    outp[base + i] = hv;
    x2[base + i] = f2bf(hv * rs * w[i]);
  }
  if (threadIdx.x == 0) rs_out[tr] = rs;
}

// single-pass register-resident softmax: bf16 scores in, bf16 P out.
// 256 threads x 4 cols = 1024 = S_; each thread loads its short4 ONCE,
// keeps values in registers across max-reduce / exp-sum-reduce / write.
__global__ __launch_bounds__(256) void softmax_k(const short* sc, short* P) {
  __shared__ float sbuf[4];
  long long row = blockIdx.x;                      // h*1024+q
  int q = (int)(row & (S_ - 1));
  const short* sr = sc + row * S_;
  short* pr = P + row * S_;
  int L = q + 1;
  int Lcap = (q & ~127) + 128;                     // PV never reads beyond this
  int c0 = threadIdx.x * 4;
  short4 sv = *(const short4*)&sr[c0];
  float v0 = (c0 + 0 < L) ? bf2f(sv.x) : -3.4e38f;
  float v1 = (c0 + 1 < L) ? bf2f(sv.y) : -3.4e38f;
  float v2 = (c0 + 2 < L) ? bf2f(sv.z) : -3.4e38f;
  float v3 = (c0 + 3 < L) ? bf2f(sv.w) : -3.4e38f;
  float mx = fmaxf(fmaxf(v0, v1), fmaxf(v2, v3));
  mx = block_reduce<true>(mx, sbuf);
  float e0 = (c0 + 0 < L) ? __expf(v0 - mx) : 0.f;
  float e1 = (c0 + 1 < L) ? __expf(v1 - mx) : 0.f;
  float e2 = (c0 + 2 < L) ? __expf(v2 - mx) : 0.f;
  float e3 = (c0 + 3 < L) ? __expf(v3 - mx) : 0.f;
  float s = block_reduce<false>(e0 + e1 + e2 + e3, sbuf);
  float inv = 1.f / s;
  if (c0 < Lcap) {
    short4 ov;
    ov.x = f2bf(e0 * inv); ov.y = f2bf(e1 * inv);
    ov.z = f2bf(e2 * inv); ov.w = f2bf(e3 * inv);
    *(short4*)&pr[c0] = ov;
  }
}

__global__ void router_k(const float* h2, const float* rs, const float* w2,
                         const float* rw, const float* sgw,
                         int* top_i, float* top_w, float* sg_sig, int* counts) {
  int t = blockIdx.x;
  int l = threadIdx.x;   // 64 threads
  float le[8] = {0, 0, 0, 0, 0, 0, 0, 0};
  float ls = 0.f;
  float r = rs[t];
  for (int k = l; k < H_; k += 64) {
    float xv = h2[(long long)t * H_ + k] * r * w2[k];
    ls += xv * sgw[k];
    const float* rk = rw + k * E_;
    #pragma unroll
    for (int e = 0; e < E_; e++) le[e] += xv * rk[e];
  }
  #pragma unroll
  for (int o = 32; o >= 1; o >>= 1) {
    ls += __shfl_down(ls, o);
    #pragma unroll
    for (int e = 0; e < E_; e++) le[e] += __shfl_down(le[e], o);
  }
  if (l == 0) {
    float m = le[0];
    for (int e = 1; e < E_; e++) m = fmaxf(m, le[e]);
    float pe[8], s = 0.f;
    for (int e = 0; e < E_; e++) { pe[e] = __expf(le[e] - m); s += pe[e]; }
    float inv = 1.f / s;
    for (int e = 0; e < E_; e++) pe[e] *= inv;
    int i1 = 0;
    for (int e = 1; e < E_; e++) if (pe[e] > pe[i1]) i1 = e;
    int i2 = -1;
    for (int e = 0; e < E_; e++) if (e != i1 && (i2 < 0 || pe[e] > pe[i2])) i2 = e;
    top_i[2 * t] = i1; top_i[2 * t + 1] = i2;
    top_w[2 * t] = pe[i1]; top_w[2 * t + 1] = pe[i2];
    sg_sig[t] = 1.f / (1.f + __expf(-ls));
    atomicAdd(&counts[i1], 1); atomicAdd(&counts[i2], 1);
  }
}

__global__ void scan_k(const int* counts, int* offs) {
  if (threadIdx.x == 0 && blockIdx.x == 0) {
    int s = 0;
    for (int e = 0; e < E_; e++) { offs[e] = s; s += counts[e]; }
  }
}

__global__ __launch_bounds__(256) void fill_k(const int* top_i, const float* top_w, const int* offs,
                                              int* pos, int* list, float* pw) {
  int t = blockIdx.x * 256 + threadIdx.x;
  if (t >= S_) return;
  for (int j = 0; j < 2; j++) {
    int e = top_i[2 * t + j];
    int p_ = atomicAdd(&pos[e], 1);
    int slot = offs[e] + p_;
    list[slot] = t; pw[slot] = top_w[2 * t + j];
  }
}

// ---------- host ----------
static GemmP mkp() {
  GemmP p{};
  p.adiv = 1; p.bdiv = 1; p.cdiv = 1; p.alpha = 1.f;
  p.ksplit = 1; p.kchunk = 1 << 30;
  p.upoff = 0; p.kstrideC = 0;
  return p;
}

extern "C" void kernel_launch(void* const* d_in, const int* in_sizes, int n_in,
                              void* d_out, int out_size, void* d_ws, size_t ws_size,
                              hipStream_t stream) {
  const float* hidden   = (const float*)d_in[0];
  const int*   pos_ids  = (const int*)d_in[1];
  const float* ln1_w    = (const float*)d_in[2];
  const float* ln2_w    = (const float*)d_in[3];
  const float* q_w      = (const float*)d_in[4];
  const float* q_b      = (const float*)d_in[5];
  const float* k_w      = (const float*)d_in[6];
  const float* k_b      = (const float*)d_in[7];
  const float* v_w      = (const float*)d_in[8];
  const float* v_b      = (const float*)d_in[9];
  const float* o_w      = (const float*)d_in[10];
  const float* router_w = (const float*)d_in[11];
  const float* e_gate   = (const float*)d_in[12];
  const float* e_up     = (const float*)d_in[13];
  const float* e_down   = (const float*)d_in[14];
  const float* s_gate   = (const float*)d_in[15];
  const float* s_up     = (const float*)d_in[16];
  const float* s_down   = (const float*)d_in[17];
  const float* sg_w     = (const float*)d_in[18];
  float* out = (float*)d_out;

  char* base = (char*)d_ws;
  size_t off_ = 0;
  auto alc = [&](size_t nbytes) -> char* {
    off_ = (off_ + 255) & ~(size_t)255;
    char* p = base + off_;
    off_ += nbytes;
    return p;
  };
  short* qkvT = (short*)alc((size_t)3072 * H_ * 2);
  short* oT   = (short*)alc((size_t)H_ * H_ * 2);
  short* eguT = (short*)alc((size_t)E_ * 2816 * H_ * 2);
  short* edT  = (short*)alc((size_t)E_ * H_ * IM_ * 2);
  short* sguT = (short*)alc((size_t)11264 * H_ * 2);
  short* sdT  = (short*)alc((size_t)H_ * ISH_ * 2);
  short* x1      = (short*)alc((size_t)S_ * H_ * 2);
  float* qkv_p   = (float*)alc((size_t)2 * S_ * 3072 * 4);   // QKV split-K partials
  float* o_part  = (float*)alc((size_t)2 * S_ * H_ * 4);     // O-proj split-K partials
  float* pv_part = (float*)alc((size_t)4 * S_ * H_ * 4);     // PV split-K partials
  float* biasCat = (float*)alc(3072 * 4);
  float* ct      = (float*)alc((size_t)S_ * 64 * 4);
  float* st      = (float*)alc((size_t)S_ * 64 * 4);
  short* qr      = (short*)alc((size_t)S_ * H_ * 2);
  short* kr      = (short*)alc((size_t)S_ * 512 * 2);
  short* vt      = (short*)alc((size_t)S_ * 512 * 2);
  short* attn    = (short*)alc((size_t)S_ * H_ * 2);
  short* x2      = (short*)alc((size_t)S_ * H_ * 2);
  float* rs2     = (float*)alc(S_ * 4);
  int*   top_i   = (int*)alc(2 * S_ * 4);
  float* top_w   = (float*)alc(2 * S_ * 4);
  float* sg_sig  = (float*)alc(S_ * 4);
  int*   counts  = (int*)alc(64);
  int*   pos     = counts + 8;
  int*   offs    = (int*)alc(32);
  int*   list    = (int*)alc(2 * S_ * 4);
  float* pw      = (float*)alc(2 * S_ * 4);
  char*  region  = alc(100663296);   // 96 MiB overlay
  short* scoresB = (short*)region;                            // 32 MiB bf16 scores
  short* P       = (short*)(region + 67108864);               // 32 MiB
  short* gu_moeB = (short*)region;                            // reuse after attn
  short* gushB   = (short*)(region + 16777216);

  // ---- MoE weight transpose descriptors (co-dispatched with attn GEMMs) ----
  TransMoE tm{};
  int tb = 0;
  {
    auto addm = [&](int i, const float* s, short* d, int R, int C, int tz,
                    long long sZ, long long dZ) {
      int tx = C / 64, ty = R / 64;
      tm.d[i] = TransDesc{s, d, R, C, tx, tx * ty, tb, sZ, dZ};
      tb += tx * ty * tz;
    };
    addm(0, e_gate, eguT, H_, IM_, E_, (long long)H_ * IM_, (long long)2816 * H_);
    addm(1, e_up, eguT + (size_t)1408 * H_, H_, IM_, E_, (long long)H_ * IM_, (long long)2816 * H_);
    addm(2, e_down, edT, IM_, H_, E_, (long long)IM_ * H_, (long long)IM_ * H_);
    addm(3, s_gate, sguT, H_, ISH_, 1, 0, 0);
    addm(4, s_up, sguT + (size_t)5632 * H_, H_, ISH_, 1, 0, 0);
    addm(5, s_down, sdT, ISH_, H_, 1, 0, 0);
    // tb = 25344 total
  }
  const int T_QKV = 12096;   // 63 slices x 192
  const int T_SC  = 6528;    // 102 slices x 64
  const int T_O   = tb - T_QKV - T_SC;   // 6720 -> 53 slices x 128

  // 0) mega dispatch: attn weight transposes (qkv,o) + prep + rmsnorm1
  {
    TransAttn ta{};
    int b = 0;
    auto add = [&](int i, const float* s, short* d, int R, int C) {
      int tx = C / 64, ty = R / 64;
      ta.d[i] = TransDesc{s, d, R, C, tx, tx * ty, b, 0, 0};
      b += tx * ty;
    };
    add(0, q_w, qkvT, H_, H_);
    add(1, k_w, qkvT + (size_t)2048 * H_, H_, 512);
    add(2, v_w, qkvT + (size_t)2560 * H_, H_, 512);
    add(3, o_w, oT, H_, H_);
    mega_k<<<b + 256 + 1024, 256, 0, stream>>>(ta, b, pos_ids, ct, st, q_b, k_b, v_b,
                                               biasCat, counts, hidden, ln1_w, x1);
  }

  // 2) fused QKV projection (split-K=2 partials) + MoE transpose slices
  {
    GemmP p = mkp();
    p.A = x1; p.lda = H_;
    p.B = qkvT; p.ldb = H_;
    p.C = qkv_p; p.kstrideC = (long long)S_ * 3072; p.ldc = 3072;
    p.M = S_; p.N = 3072; p.K = H_;
    p.ksplit = 2; p.kchunk = 1024;
    gemm_tr<0><<<dim3(24, 8, 2 + 63), 256, 0, stream>>>(p, tm, 2, 0, T_QKV);
  }

  // 3) fused RoPE(q,k) + V transpose, reducing the partials (p0+p1+bias)
  rope_fused_k<<<12288, 256, 0, stream>>>(qkv_p, qkv_p + (size_t)S_ * 3072, biasCat,
                                          qr, kr, vt, ct, st);

  // 4) scores = scale * Q K^T -> bf16 (causal tiles) + MoE transpose slices
  {
    GemmP p = mkp();
    p.A = qr; p.strideA = HD_; p.lda = H_;
    p.B = kr; p.strideB = HD_; p.bdiv = 4; p.ldb = 512;
    p.C = scoresB; p.strideC = (long long)S_ * S_; p.ldc = S_;
    p.alpha = 0.08838834764831845f;
    p.M = S_; p.N = S_; p.K = HD_; p.cskip = 1;
    gemm_tr<2><<<dim3(8, 8, NH_ + 102), 256, 0, stream>>>(p, tm, NH_, T_QKV, T_SC);
  }
  softmax_k<<<NH_ * S_, 256, 0, stream>>>(scoresB, P);
  // 5) attn = P @ V: deterministic split-K=4 -> pv_part, then fixed-order reduce
  {
    GemmP p = mkp();
    p.A = P; p.strideA = (long long)S_ * S_; p.lda = S_;
    p.B = vt; p.strideB = (long long)HD_ * S_; p.bdiv = 4; p.ldb = S_;
    p.C = pv_part; p.strideC = HD_; p.kstrideC = (long long)S_ * H_; p.ldc = H_;
    p.M = S_; p.N = HD_; p.K = S_; p.ckb = 1;
    p.ksplit = 4; p.kchunk = 256;
    gemm_bt<0><<<dim3(1, 8, NH_ * 4), 256, 0, stream>>>(p);
  }
  pv_red_k<<<8192, 256, 0, stream>>>(pv_part, attn);
  // 6) O-proj (split-K=2 partials) + remaining MoE transpose slices
  {
    GemmP p = mkp();
    p.A = attn; p.lda = H_;
    p.B = oT; p.ldb = H_;
    p.C = o_part; p.kstrideC = (long long)S_ * H_; p.ldc = H_;
    p.M = S_; p.N = H_; p.K = H_;
    p.ksplit = 2; p.kchunk = 1024;
    gemm_tr<0><<<dim3(16, 8, 2 + 53), 256, 0, stream>>>(p, tm, 2, T_QKV + T_SC, T_O);
  }

  // 7) rmsnorm2 fused with O-partial reduction: out = h2 = p0+p1+hidden;
  //    x2 = bf16(h2*rs*ln2_w); rs2. Deterministic -> stable router top-2.
  rmsnorm2f_k<<<S_, 256, 0, stream>>>(o_part, o_part + (size_t)S_ * H_, hidden,
                                      ln2_w, x2, out, rs2);

  // 8) router / top-2 / gather lists (reads out == h2; counts pre-zeroed in mega_k)
  router_k<<<S_, 64, 0, stream>>>(out, rs2, ln2_w, router_w, sg_w, top_i, top_w, sg_sig, counts);
  scan_k<<<1, 1, 0, stream>>>(counts, offs);
  fill_k<<<4, 256, 0, stream>>>(top_i, top_w, offs, pos, list, pw);

  // 9) MERGED gate+up+silu: expert (z<8, 22 n-tiles) + shared (z 8..11, n-tile
  //    = (z-8)*22+x) -> 2112 blocks, zero dead blocks.
  {
    GemmP pe = mkp();
    pe.A = x2; pe.lda = H_;
    pe.B = eguT; pe.strideB = (long long)2816 * H_; pe.ldb = H_;
    pe.C = gu_moeB; pe.ldc = IM_;
    pe.e_off = offs; pe.e_cnt = counts; pe.list = list;
    pe.M = S_; pe.N = IM_; pe.K = H_;
    pe.upoff = IM_;
    GemmP ps = mkp();
    ps.A = x2; ps.lda = H_;
    ps.B = sguT; ps.ldb = H_;
    ps.C = gushB; ps.ldc = ISH_;
    ps.M = S_; ps.N = ISH_; ps.K = H_;
    ps.upoff = ISH_;
    gemm_gu_dual<<<dim3(22, 8, 12), 256, 0, stream>>>(pe, ps);
  }

  // 10) MERGED down-projections: expert scatter-add (z<16) + shared (z 16..19).
  //     atomicAdd here is rounding-level nondeterminism only (continuous path).
  {
    GemmP pe = mkp();
    pe.A = gu_moeB; pe.lda = IM_;
    pe.B = edT; pe.strideB = (long long)H_ * IM_; pe.ldb = IM_;
    pe.C = out; pe.ldc = H_;
    pe.e_off = offs; pe.e_cnt = counts; pe.list = list; pe.scale = pw;
    pe.M = S_; pe.N = H_; pe.K = IM_;
    pe.ksplit = 2; pe.kchunk = 704;
    GemmP ps = mkp();
    ps.A = gushB; ps.lda = ISH_;
    ps.B = sdT; ps.ldb = ISH_;
    ps.C = out; ps.ldc = H_; ps.scale = sg_sig;
    ps.M = S_; ps.N = H_; ps.K = ISH_;
    ps.ksplit = 4; ps.kchunk = 1408;
    gemm_dual<4, 5><<<dim3(16, 8, E_ * 2 + 4), 256, 0, stream>>>(pe, ps, E_ * 2);
  }
}